// Round 11
// baseline (450.769 us; speedup 1.0000x reference)
//
#include <hip/hip_runtime.h>

typedef short bf16x8 __attribute__((ext_vector_type(8)));
typedef float f32x4 __attribute__((ext_vector_type(4)));

// Problem constants
// B=16, N=1024, D=768, H=12, HD=64, NUM_BUCKETS=49, SCALE=0.125
// Q is pre-scaled by SCALE*log2(e) so softmax runs in exp2 domain.
#define QSCALE 0.1803368801111204f

__device__ __forceinline__ unsigned short f2bf(float f){
  unsigned u = __float_as_uint(f);
  u = (u + 0x7fffu + ((u >> 16) & 1u)) >> 16;   // round-nearest-even
  return (unsigned short)u;
}
__device__ __forceinline__ f32x4 mfma16(bf16x8 a, bf16x8 b, f32x4 c){
  return __builtin_amdgcn_mfma_f32_16x16x32_bf16(a, b, c, 0, 0, 0);
}
__device__ __forceinline__ void gload_lds16(const void* g, void* l){
  __builtin_amdgcn_global_load_lds((__attribute__((address_space(1))) void*)(g),
                                   (__attribute__((address_space(3))) void*)(l), 16, 0, 0);
}
__device__ __forceinline__ unsigned cvt_pk_bf16(float lo, float hi){
  unsigned r;
  asm("v_cvt_pk_bf16_f32 %0, %1, %2" : "=v"(r) : "v"(lo), "v"(hi));
  return r;
}
// v_exp_f32 computes 2^x natively on gfx950 (cdna4_isa §3)
__device__ __forceinline__ float exp2_fast(float x){
  float r;
  asm("v_exp_f32 %0, %1" : "=v"(r) : "v"(x));
  return r;
}

// ---------------------------------------------------------------------------
// prep: f32 -> bf16 conversions + rp_bucket -> pre-swizzled byte offsets
// rp8[i][j] = (bucket*2) ^ ((i&7)<<4)  (byte offset into swizzled bf16 bias row)
// ---------------------------------------------------------------------------
__global__ __launch_bounds__(256) void prep_kernel(
    const float* __restrict__ x, const float* __restrict__ qw,
    const float* __restrict__ pw, const int* __restrict__ rp,
    unsigned short* __restrict__ xb, unsigned short* __restrict__ wb,
    unsigned short* __restrict__ pwb, unsigned char* __restrict__ rp8){
  const int T1 = 3145728;            // 16384*768/4
  const int T2 = T1 + 442368;        // + 2304*768/4
  const int T3 = T2 + 147456;        // + 768*768/4
  const int T4 = T3 + 262144;        // + 1024*1024/4
  for (int t = blockIdx.x * 256 + threadIdx.x; t < T4; t += gridDim.x * 256){
    if (t < T3){
      const float4* src; ushort4* dst; int off;
      if (t < T1){ src = (const float4*)x;  dst = (ushort4*)xb;  off = t; }
      else if (t < T2){ src = (const float4*)qw; dst = (ushort4*)wb;  off = t - T1; }
      else { src = (const float4*)pw; dst = (ushort4*)pwb; off = t - T2; }
      float4 v = src[off];
      ushort4 u;
      u.x = f2bf(v.x); u.y = f2bf(v.y); u.z = f2bf(v.z); u.w = f2bf(v.w);
      dst[off] = u;
    } else {
      int off = t - T3;
      int4 v = ((const int4*)rp)[off];
      int row = (off * 4) >> 10;               // all 4 j's share the row
      int sw = (row & 7) << 4;
      uchar4 u;
      u.x = (unsigned char)((v.x << 1) ^ sw);
      u.y = (unsigned char)((v.y << 1) ^ sw);
      u.z = (unsigned char)((v.z << 1) ^ sw);
      u.w = (unsigned char)((v.w << 1) ^ sw);
      ((uchar4*)rp8)[off] = u;
    }
  }
}

// ---------------------------------------------------------------------------
// Shared NT-GEMM core: C[128x128] tile, A[M][K], B[N][K] both bf16 K-contig.
// m97 structure: BK=32, global_load_lds(16B) staging, 4 waves 2x2.
// ---------------------------------------------------------------------------
__device__ __forceinline__ void gemm_core(
    const unsigned short* __restrict__ A, const unsigned short* __restrict__ Bm,
    int m0, int n0, int K, unsigned short* As, unsigned short* Bs,
    f32x4 (&acc)[4][4]){
  const int tid = threadIdx.x, lane = tid & 63, wave = tid >> 6;
  const int g = lane >> 4, r16 = lane & 15;
  const int wr = wave >> 1, wc = wave & 1;
  for (int k0 = 0; k0 < K; k0 += 32){
    __syncthreads();
    #pragma unroll
    for (int j = 0; j < 2; j++){
      int ci = j * 256 + tid;          // chunk id, 512 chunks of 16B per tile
      int row = ci >> 2, c = ci & 3;   // 4 chunks (64B) per row
      gload_lds16(A  + (size_t)(m0 + row) * K + k0 + c * 8,
                  (char*)As + (j * 256 + wave * 64) * 16);
      gload_lds16(Bm + (size_t)(n0 + row) * K + k0 + c * 8,
                  (char*)Bs + (j * 256 + wave * 64) * 16);
    }
    __syncthreads();
    bf16x8 a[4], b[4];
    #pragma unroll
    for (int mi = 0; mi < 4; mi++)
      a[mi] = *(const bf16x8*)((const char*)As + (wr * 64 + mi * 16 + r16) * 64 + g * 16);
    #pragma unroll
    for (int ni = 0; ni < 4; ni++)
      b[ni] = *(const bf16x8*)((const char*)Bs + (wc * 64 + ni * 16 + r16) * 64 + g * 16);
    #pragma unroll
    for (int mi = 0; mi < 4; mi++)
      #pragma unroll
      for (int ni = 0; ni < 4; ni++)
        acc[mi][ni] = mfma16(a[mi], b[ni], acc[mi][ni]);
  }
}

// ---------------------------------------------------------------------------
// QKV projection: qkv = x @ qkv_w^T ; route to Q(*QSCALE)[B,H,N,HD],
// K[B,H,N,HD], V^T[B,H,HD,N], all bf16.
// ---------------------------------------------------------------------------
__global__ __launch_bounds__(256) void qkv_gemm(
    const unsigned short* __restrict__ xb, const unsigned short* __restrict__ wb,
    unsigned short* __restrict__ q_s, unsigned short* __restrict__ k_s,
    unsigned short* __restrict__ v_t){
  __shared__ __align__(16) unsigned short As[128 * 32];
  __shared__ __align__(16) unsigned short Bs[128 * 32];
  f32x4 acc[4][4];
  #pragma unroll
  for (int i = 0; i < 4; i++)
    #pragma unroll
    for (int j = 0; j < 4; j++){
      acc[i][j][0] = 0.f; acc[i][j][1] = 0.f; acc[i][j][2] = 0.f; acc[i][j][3] = 0.f;
    }
  const int m0 = blockIdx.y * 128, n0 = blockIdx.x * 128;
  gemm_core(xb, wb, m0, n0, 768, As, Bs, acc);

  const int lane = threadIdx.x & 63, wave = threadIdx.x >> 6;
  const int g = lane >> 4, r16 = lane & 15;
  const int wr = wave >> 1, wc = wave & 1;
  #pragma unroll
  for (int mi = 0; mi < 4; mi++){
    #pragma unroll
    for (int ni = 0; ni < 4; ni++){
      int gcol = n0 + wc * 64 + ni * 16 + r16;      // 0..2303 = [3][12][64]
      int sel = gcol / 768;
      int rem = gcol - sel * 768;
      int h = rem >> 6, hd = rem & 63;
      #pragma unroll
      for (int r = 0; r < 4; r++){
        int grow = m0 + wr * 64 + mi * 16 + 4 * g + r;   // 0..16383 = [16][1024]
        int bb = grow >> 10, ii = grow & 1023;
        size_t base = ((size_t)(bb * 12 + h)) << 16;     // *1024*64
        float v = acc[mi][ni][r];
        if (sel == 0)      q_s[base + ((size_t)ii << 6) + hd] = f2bf(v * QSCALE);
        else if (sel == 1) k_s[base + ((size_t)ii << 6) + hd] = f2bf(v);
        else               v_t[base + ((size_t)hd << 10) + ii] = f2bf(v);
      }
    }
  }
}

// ---------------------------------------------------------------------------
// Flash attention with relative-position bias (exp2-domain online softmax,
// defer-max THR=8, pre-swizzled bucket byte offsets, bf16 bias table in LDS).
// K-fragments are loaded global->register inside the staging window (they
// drain at the same vmcnt(0)+barrier that V staging already pays) -> 8 of 18
// ds_read_b128 per wave-step removed, LDS 24KB.
// ---------------------------------------------------------------------------
__global__ __launch_bounds__(256) void attn_kernel(
    const unsigned short* __restrict__ q_s, const unsigned short* __restrict__ k_s,
    const unsigned short* __restrict__ v_t, const unsigned char* __restrict__ rp8,
    const float* __restrict__ rpe, unsigned short* __restrict__ ao){
  // LDS layout (24576 B):
  //   [0,8192)      vs  : V^T tile [64 d][64 j] bf16, XOR-swizzled
  //   [8192,16384)  pbuf: per-wave P [16 i][64 j] bf16, XOR-swizzled
  //   [16384,24576) bias: [64 row][64 bucket] bf16, byte (c*2)^((row&7)<<4)
  __shared__ __align__(16) char smem[24576];
  const int tid = threadIdx.x, lane = tid & 63, w = tid >> 6;
  const int g = lane >> 4, r16 = lane & 15;
  const int qb = blockIdx.x, bh = blockIdx.y;
  const size_t bh_base = (size_t)bh << 16;   // *1024*64 elements

  // ---- Q fragments (B-operand): lane holds Q[i_loc][kc*32 + 8g .. +7] ----
  const int i_loc = w * 16 + r16;
  const size_t qoff = bh_base + ((size_t)(qb * 64 + i_loc) << 6);
  bf16x8 qf0 = *(const bf16x8*)(q_s + qoff + g * 8);
  bf16x8 qf1 = *(const bf16x8*)(q_s + qoff + 32 + g * 8);

  // ---- bias[i][c] = q_i . rpe_c via MFMA; bf16, swizzled; wave-private ----
  char* bias_lds = smem + 16384;
  const int s16 = (r16 & 7) << 4;            // byte-unit row swizzle
  #pragma unroll
  for (int jt = 0; jt < 4; jt++){
    int crow = jt * 16 + r16;                // bucket index (A row)
    bf16x8 a0, a1;
    #pragma unroll
    for (int e = 0; e < 8; e++){ a0[e] = 0; a1[e] = 0; }
    if (crow < 49){
      const float* rr = rpe + crow * 64 + g * 8;
      float4 x0 = *(const float4*)(rr);
      float4 x1 = *(const float4*)(rr + 4);
      float4 y0 = *(const float4*)(rr + 32);
      float4 y1 = *(const float4*)(rr + 36);
      a0[0]=f2bf(x0.x); a0[1]=f2bf(x0.y); a0[2]=f2bf(x0.z); a0[3]=f2bf(x0.w);
      a0[4]=f2bf(x1.x); a0[5]=f2bf(x1.y); a0[6]=f2bf(x1.z); a0[7]=f2bf(x1.w);
      a1[0]=f2bf(y0.x); a1[1]=f2bf(y0.y); a1[2]=f2bf(y0.z); a1[3]=f2bf(y0.w);
      a1[4]=f2bf(y1.x); a1[5]=f2bf(y1.y); a1[6]=f2bf(y1.z); a1[7]=f2bf(y1.w);
    }
    f32x4 z = {0.f, 0.f, 0.f, 0.f};
    z = mfma16(a0, qf0, z);
    z = mfma16(a1, qf1, z);
    uint2 u; u.x = cvt_pk_bf16(z[0], z[1]); u.y = cvt_pk_bf16(z[2], z[3]);
    *(uint2*)(bias_lds + i_loc * 128 + ((jt * 32 + 8 * g) ^ s16)) = u;
  }

  unsigned short* vs = (unsigned short*)smem;
  char* pbuf = smem + 8192 + w * 2048;
  const char* browb = bias_lds + i_loc * 128;

  // V staging pointers (per-thread); K-fragment global pointer (per-lane)
  const int ci0 = tid, ci1 = 256 + tid;
  const int row0 = ci0 >> 3, sc0 = (ci0 & 7) ^ (row0 & 7);
  const int row1 = ci1 >> 3, sc1 = (ci1 & 7) ^ (row1 & 7);
  const char* vp0 = (const char*)(v_t + bh_base) + row0 * 2048 + sc0 * 16;
  const char* vp1 = (const char*)(v_t + bh_base) + row1 * 2048 + sc1 * 16;
  char* vl0 = (char*)smem + w * 1024;
  char* vl1 = (char*)smem + 4096 + w * 1024;
  const unsigned short* kbase = k_s + bh_base + r16 * 64 + g * 8; // +jt*1024 +kb*4096
  const unsigned char* rprow = rp8 + ((size_t)(qb * 64 + i_loc) << 10);

  f32x4 o[4];
  #pragma unroll
  for (int dt = 0; dt < 4; dt++){ o[dt][0]=0.f; o[dt][1]=0.f; o[dt][2]=0.f; o[dt][3]=0.f; }
  float m_i = -INFINITY, l_i = 0.f;

  for (int kb = 0; kb < 16; kb++){
    __syncthreads();
    // stage V(kb) into LDS; load K(kb) fragments straight into registers.
    // Both drain at the barrier below (already vmcnt(0) for the gload_lds).
    gload_lds16(vp0, vl0);
    gload_lds16(vp1, vl1);
    vp0 += 128; vp1 += 128;
    const unsigned short* kp = kbase + kb * 4096;
    bf16x8 ka0[4], ka1[4];
    #pragma unroll
    for (int jt = 0; jt < 4; jt++){
      ka0[jt] = *(const bf16x8*)(kp + jt * 1024);
      ka1[jt] = *(const bf16x8*)(kp + jt * 1024 + 32);
    }
    __syncthreads();

    // S^T = K . Q^T : lane holds S[i_loc][j = kb*64 + 16jt + 4g + r]
    f32x4 st[4];
    #pragma unroll
    for (int jt = 0; jt < 4; jt++){
      f32x4 z = {0.f, 0.f, 0.f, 0.f};
      z = mfma16(ka0[jt], qf0, z);
      z = mfma16(ka1[jt], qf1, z);
      st[jt] = z;
    }
    // relative-position bias gather (pre-swizzled byte offsets, bf16 table)
    #pragma unroll
    for (int jt = 0; jt < 4; jt++){
      unsigned bu = *(const unsigned*)(rprow + kb * 64 + jt * 16 + g * 4);
      st[jt][0] += __uint_as_float((unsigned)*(const unsigned short*)(browb + (bu & 0xff)) << 16);
      st[jt][1] += __uint_as_float((unsigned)*(const unsigned short*)(browb + ((bu >> 8) & 0xff)) << 16);
      st[jt][2] += __uint_as_float((unsigned)*(const unsigned short*)(browb + ((bu >> 16) & 0xff)) << 16);
      st[jt][3] += __uint_as_float((unsigned)*(const unsigned short*)(browb + (bu >> 24)) << 16);
    }
    // online softmax, exp2 domain (row stats in lanes sharing r16)
    float tmax = -INFINITY;
    #pragma unroll
    for (int jt = 0; jt < 4; jt++)
      tmax = fmaxf(tmax, fmaxf(fmaxf(st[jt][0], st[jt][1]), fmaxf(st[jt][2], st[jt][3])));
    tmax = fmaxf(tmax, __shfl_xor(tmax, 16));
    tmax = fmaxf(tmax, __shfl_xor(tmax, 32));
    const bool skip = __all(tmax <= m_i + 8.f);   // defer-max: P bounded by 2^8
    if (!skip){
      float mnew = fmaxf(m_i, tmax);
      float alpha = exp2_fast(m_i - mnew);
      m_i = mnew;
      l_i *= alpha;
      float af[4];
      #pragma unroll
      for (int r = 0; r < 4; r++) af[r] = __shfl(alpha, 4 * g + r);
      #pragma unroll
      for (int dt = 0; dt < 4; dt++){
        o[dt][0] *= af[0]; o[dt][1] *= af[1]; o[dt][2] *= af[2]; o[dt][3] *= af[3];
      }
    }
    // P = exp2(S - m), lane-partial l accumulate, pack to pbuf
    #pragma unroll
    for (int jt = 0; jt < 4; jt++){
      float p0 = exp2_fast(st[jt][0] - m_i);
      float p1 = exp2_fast(st[jt][1] - m_i);
      float p2 = exp2_fast(st[jt][2] - m_i);
      float p3 = exp2_fast(st[jt][3] - m_i);
      l_i += (p0 + p1) + (p2 + p3);
      uint2 u; u.x = cvt_pk_bf16(p0, p1); u.y = cvt_pk_bf16(p2, p3);
      *(uint2*)(pbuf + r16 * 128 + ((jt * 32 + g * 8) ^ ((r16 & 7) << 4))) = u;
    }
    // O += P . V  (A = P from per-wave LDS, B = V^T rows = contiguous j)
    #pragma unroll
    for (int kt = 0; kt < 2; kt++){
      bf16x8 pa = *(const bf16x8*)(pbuf + r16 * 128 + ((kt * 64 + g * 16) ^ ((r16 & 7) << 4)));
      #pragma unroll
      for (int dt = 0; dt < 4; dt++){
        int vrow = dt * 16 + r16;
        bf16x8 vb = *(const bf16x8*)((const char*)vs + vrow * 128 + ((kt * 64 + g * 16) ^ ((vrow & 7) << 4)));
        o[dt] = mfma16(pa, vb, o[dt]);
      }
    }
  }

  // finalize: reduce l across g, divide by l, store bf16 to [b, i, h*64+d]
  l_i += __shfl_xor(l_i, 16);
  l_i += __shfl_xor(l_i, 32);
  float lf[4];
  #pragma unroll
  for (int r = 0; r < 4; r++) lf[r] = 1.f / __shfl(l_i, 4 * g + r);
  const int bidx = bh / 12, h = bh - bidx * 12;
  #pragma unroll
  for (int dt = 0; dt < 4; dt++){
    int d = dt * 16 + r16;
    #pragma unroll
    for (int r = 0; r < 4; r++){
      int i = qb * 64 + w * 16 + 4 * g + r;
      ao[(size_t)(bidx * 1024 + i) * 768 + h * 64 + d] = f2bf(o[dt][r] * lf[r]);
    }
  }
}

// ---------------------------------------------------------------------------
// Output projection: out = attn_out @ proj_w^T + proj_b  (f32 out)
// ---------------------------------------------------------------------------
__global__ __launch_bounds__(256) void proj_gemm(
    const unsigned short* __restrict__ aob, const unsigned short* __restrict__ pwb,
    const float* __restrict__ pb, float* __restrict__ out){
  __shared__ __align__(16) unsigned short As[128 * 32];
  __shared__ __align__(16) unsigned short Bs[128 * 32];
  f32x4 acc[4][4];
  #pragma unroll
  for (int i = 0; i < 4; i++)
    #pragma unroll
    for (int j = 0; j < 4; j++){
      acc[i][j][0] = 0.f; acc[i][j][1] = 0.f; acc[i][j][2] = 0.f; acc[i][j][3] = 0.f;
    }
  const int m0 = blockIdx.y * 128, n0 = blockIdx.x * 128;
  gemm_core(aob, pwb, m0, n0, 768, As, Bs, acc);

  const int lane = threadIdx.x & 63, wave = threadIdx.x >> 6;
  const int g = lane >> 4, r16 = lane & 15;
  const int wr = wave >> 1, wc = wave & 1;
  #pragma unroll
  for (int mi = 0; mi < 4; mi++){
    #pragma unroll
    for (int ni = 0; ni < 4; ni++){
      int gcol = n0 + wc * 64 + ni * 16 + r16;
      float bias = pb[gcol];
      #pragma unroll
      for (int r = 0; r < 4; r++){
        int grow = m0 + wr * 64 + mi * 16 + 4 * g + r;
        out[(size_t)grow * 768 + gcol] = acc[mi][ni][r] + bias;
      }
    }
  }
}

// ---------------------------------------------------------------------------
extern "C" void kernel_launch(void* const* d_in, const int* in_sizes, int n_in,
                              void* d_out, int out_size, void* d_ws, size_t ws_size,
                              hipStream_t stream){
  const float* x      = (const float*)d_in[0];
  const float* qkv_w  = (const float*)d_in[1];
  const float* rpe    = (const float*)d_in[2];
  const int*   rp     = (const int*)d_in[3];
  const float* proj_w = (const float*)d_in[4];
  const float* proj_b = (const float*)d_in[5];
  float* out = (float*)d_out;
  char* ws = (char*)d_ws;

  unsigned short* xb  = (unsigned short*)(ws);               // 25,165,824 B
  unsigned short* wb  = (unsigned short*)(ws + 25165824);    //  3,538,944 B
  unsigned short* pwb = (unsigned short*)(ws + 28704768);    //  1,179,648 B
  unsigned char*  rp8 = (unsigned char*) (ws + 29884416);    //  1,048,576 B
  unsigned short* q_s = (unsigned short*)(ws + 30932992);    // 25,165,824 B
  unsigned short* k_s = (unsigned short*)(ws + 56098816);    // 25,165,824 B
  unsigned short* v_t = (unsigned short*)(ws + 81264640);    // 25,165,824 B
  unsigned short* aob = (unsigned short*)(ws + 106430464);   // 25,165,824 B -> 131,596,288 total

  prep_kernel<<<2048, 256, 0, stream>>>(x, qkv_w, proj_w, rp, xb, wb, pwb, rp8);
  qkv_gemm<<<dim3(18, 128), 256, 0, stream>>>(xb, wb, q_s, k_s, v_t);
  attn_kernel<<<dim3(16, 192), 256, 0, stream>>>(q_s, k_s, v_t, rp8, rpe, aob);
  proj_gemm<<<dim3(6, 128), 256, 0, stream>>>(aob, pwb, proj_b, out);
}

// Round 12
// 314.286 us; speedup vs baseline: 1.4343x; 1.4343x over previous
//
#include <hip/hip_runtime.h>

typedef short bf16x8 __attribute__((ext_vector_type(8)));
typedef float f32x4 __attribute__((ext_vector_type(4)));

// Problem constants
// B=16, N=1024, D=768, H=12, HD=64, NUM_BUCKETS=49, SCALE=0.125
// Q is pre-scaled by SCALE*log2(e) so softmax runs in exp2 domain.
#define QSCALE 0.1803368801111204f

__device__ __forceinline__ unsigned short f2bf(float f){
  unsigned u = __float_as_uint(f);
  u = (u + 0x7fffu + ((u >> 16) & 1u)) >> 16;   // round-nearest-even
  return (unsigned short)u;
}
__device__ __forceinline__ f32x4 mfma16(bf16x8 a, bf16x8 b, f32x4 c){
  return __builtin_amdgcn_mfma_f32_16x16x32_bf16(a, b, c, 0, 0, 0);
}
__device__ __forceinline__ void gload_lds16(const void* g, void* l){
  __builtin_amdgcn_global_load_lds((__attribute__((address_space(1))) void*)(g),
                                   (__attribute__((address_space(3))) void*)(l), 16, 0, 0);
}
__device__ __forceinline__ unsigned cvt_pk_bf16(float lo, float hi){
  unsigned r;
  asm("v_cvt_pk_bf16_f32 %0, %1, %2" : "=v"(r) : "v"(lo), "v"(hi));
  return r;
}
// v_exp_f32 computes 2^x natively on gfx950 (cdna4_isa §3)
__device__ __forceinline__ float exp2_fast(float x){
  float r;
  asm("v_exp_f32 %0, %1" : "=v"(r) : "v"(x));
  return r;
}

// ---------------------------------------------------------------------------
// prep: f32 -> bf16 conversions + rp_bucket -> pre-swizzled byte offsets
// rp8[i][j] = (bucket*2) ^ ((i&7)<<4)  (byte offset into swizzled bf16 bias row)
// ---------------------------------------------------------------------------
__global__ __launch_bounds__(256) void prep_kernel(
    const float* __restrict__ x, const float* __restrict__ qw,
    const float* __restrict__ pw, const int* __restrict__ rp,
    unsigned short* __restrict__ xb, unsigned short* __restrict__ wb,
    unsigned short* __restrict__ pwb, unsigned char* __restrict__ rp8){
  const int T1 = 3145728;            // 16384*768/4
  const int T2 = T1 + 442368;        // + 2304*768/4
  const int T3 = T2 + 147456;        // + 768*768/4
  const int T4 = T3 + 262144;        // + 1024*1024/4
  for (int t = blockIdx.x * 256 + threadIdx.x; t < T4; t += gridDim.x * 256){
    if (t < T3){
      const float4* src; ushort4* dst; int off;
      if (t < T1){ src = (const float4*)x;  dst = (ushort4*)xb;  off = t; }
      else if (t < T2){ src = (const float4*)qw; dst = (ushort4*)wb;  off = t - T1; }
      else { src = (const float4*)pw; dst = (ushort4*)pwb; off = t - T2; }
      float4 v = src[off];
      ushort4 u;
      u.x = f2bf(v.x); u.y = f2bf(v.y); u.z = f2bf(v.z); u.w = f2bf(v.w);
      dst[off] = u;
    } else {
      int off = t - T3;
      int4 v = ((const int4*)rp)[off];
      int row = (off * 4) >> 10;               // all 4 j's share the row
      int sw = (row & 7) << 4;
      uchar4 u;
      u.x = (unsigned char)((v.x << 1) ^ sw);
      u.y = (unsigned char)((v.y << 1) ^ sw);
      u.z = (unsigned char)((v.z << 1) ^ sw);
      u.w = (unsigned char)((v.w << 1) ^ sw);
      ((uchar4*)rp8)[off] = u;
    }
  }
}

// ---------------------------------------------------------------------------
// Shared NT-GEMM core: C[128x128] tile, A[M][K], B[N][K] both bf16 K-contig.
// m97 structure: BK=32, global_load_lds(16B) staging, 4 waves 2x2.
// ---------------------------------------------------------------------------
__device__ __forceinline__ void gemm_core(
    const unsigned short* __restrict__ A, const unsigned short* __restrict__ Bm,
    int m0, int n0, int K, unsigned short* As, unsigned short* Bs,
    f32x4 (&acc)[4][4]){
  const int tid = threadIdx.x, lane = tid & 63, wave = tid >> 6;
  const int g = lane >> 4, r16 = lane & 15;
  const int wr = wave >> 1, wc = wave & 1;
  for (int k0 = 0; k0 < K; k0 += 32){
    __syncthreads();
    #pragma unroll
    for (int j = 0; j < 2; j++){
      int ci = j * 256 + tid;          // chunk id, 512 chunks of 16B per tile
      int row = ci >> 2, c = ci & 3;   // 4 chunks (64B) per row
      gload_lds16(A  + (size_t)(m0 + row) * K + k0 + c * 8,
                  (char*)As + (j * 256 + wave * 64) * 16);
      gload_lds16(Bm + (size_t)(n0 + row) * K + k0 + c * 8,
                  (char*)Bs + (j * 256 + wave * 64) * 16);
    }
    __syncthreads();
    bf16x8 a[4], b[4];
    #pragma unroll
    for (int mi = 0; mi < 4; mi++)
      a[mi] = *(const bf16x8*)((const char*)As + (wr * 64 + mi * 16 + r16) * 64 + g * 16);
    #pragma unroll
    for (int ni = 0; ni < 4; ni++)
      b[ni] = *(const bf16x8*)((const char*)Bs + (wc * 64 + ni * 16 + r16) * 64 + g * 16);
    #pragma unroll
    for (int mi = 0; mi < 4; mi++)
      #pragma unroll
      for (int ni = 0; ni < 4; ni++)
        acc[mi][ni] = mfma16(a[mi], b[ni], acc[mi][ni]);
  }
}

// ---------------------------------------------------------------------------
// QKV projection: qkv = x @ qkv_w^T ; route to Q(*QSCALE)[B,H,N,HD],
// K[B,H,N,HD], V^T[B,H,HD,N], all bf16.
// ---------------------------------------------------------------------------
__global__ __launch_bounds__(256) void qkv_gemm(
    const unsigned short* __restrict__ xb, const unsigned short* __restrict__ wb,
    unsigned short* __restrict__ q_s, unsigned short* __restrict__ k_s,
    unsigned short* __restrict__ v_t){
  __shared__ __align__(16) unsigned short As[128 * 32];
  __shared__ __align__(16) unsigned short Bs[128 * 32];
  f32x4 acc[4][4];
  #pragma unroll
  for (int i = 0; i < 4; i++)
    #pragma unroll
    for (int j = 0; j < 4; j++){
      acc[i][j][0] = 0.f; acc[i][j][1] = 0.f; acc[i][j][2] = 0.f; acc[i][j][3] = 0.f;
    }
  const int m0 = blockIdx.y * 128, n0 = blockIdx.x * 128;
  gemm_core(xb, wb, m0, n0, 768, As, Bs, acc);

  const int lane = threadIdx.x & 63, wave = threadIdx.x >> 6;
  const int g = lane >> 4, r16 = lane & 15;
  const int wr = wave >> 1, wc = wave & 1;
  #pragma unroll
  for (int mi = 0; mi < 4; mi++){
    #pragma unroll
    for (int ni = 0; ni < 4; ni++){
      int gcol = n0 + wc * 64 + ni * 16 + r16;      // 0..2303 = [3][12][64]
      int sel = gcol / 768;
      int rem = gcol - sel * 768;
      int h = rem >> 6, hd = rem & 63;
      #pragma unroll
      for (int r = 0; r < 4; r++){
        int grow = m0 + wr * 64 + mi * 16 + 4 * g + r;   // 0..16383 = [16][1024]
        int bb = grow >> 10, ii = grow & 1023;
        size_t base = ((size_t)(bb * 12 + h)) << 16;     // *1024*64
        float v = acc[mi][ni][r];
        if (sel == 0)      q_s[base + ((size_t)ii << 6) + hd] = f2bf(v * QSCALE);
        else if (sel == 1) k_s[base + ((size_t)ii << 6) + hd] = f2bf(v);
        else               v_t[base + ((size_t)hd << 10) + ii] = f2bf(v);
      }
    }
  }
}

// ---------------------------------------------------------------------------
// Flash attention with relative-position bias.
// Block = (qb, bh): 128 q-rows, 4 waves x 32 rows (2 halves of 16).
// ka/vb LDS fragments shared across both halves (K once, V twice).
// P for the two halves goes SEQUENTIALLY through one 2KB/wave pbuf so the
// whole kernel fits 40960B LDS -> 4 blocks/CU (R5 structure at R4 occupancy).
// ---------------------------------------------------------------------------
__global__ __launch_bounds__(256) void attn_kernel(
    const unsigned short* __restrict__ q_s, const unsigned short* __restrict__ k_s,
    const unsigned short* __restrict__ v_t, const unsigned char* __restrict__ rp8,
    const float* __restrict__ rpe, unsigned short* __restrict__ ao){
  // LDS layout (40960 B, 4 blocks/CU):
  //   [0,8192)      ks  : K tile [64 j][64 hd] bf16, XOR-swizzled
  //   [8192,16384)  vs  : V^T tile [64 d][64 j] bf16, XOR-swizzled
  //   [16384,24576) pbuf: per-wave P [16 i][64 j] bf16, XOR-swizzled (reused
  //                 by both halves sequentially)
  //   [24576,40960) bias: [128 row][64 bucket] bf16, byte (c*2)^((row&7)<<4)
  __shared__ __align__(16) char smem[40960];
  const int tid = threadIdx.x, lane = tid & 63, w = tid >> 6;
  const int g = lane >> 4, r16 = lane & 15;
  const int qb = blockIdx.x, bh = blockIdx.y;
  const size_t bh_base = (size_t)bh << 16;   // *1024*64 elements
  const int iw = w * 32;                     // wave's first row (block-local)

  // ---- Q fragments: halves h=0,1; lane holds Q[row][8g..8g+7 | +32] ----
  const size_t q0 = bh_base + ((size_t)(qb * 128 + iw + r16) << 6);
  bf16x8 qf[4];
  qf[0] = *(const bf16x8*)(q_s + q0 + g * 8);
  qf[1] = *(const bf16x8*)(q_s + q0 + 32 + g * 8);
  qf[2] = *(const bf16x8*)(q_s + q0 + 1024 + g * 8);        // +16 rows
  qf[3] = *(const bf16x8*)(q_s + q0 + 1024 + 32 + g * 8);

  // ---- bias[i][c] = q_i . rpe_c via MFMA; store bf16 swizzled ----
  char* bias_lds = smem + 24576;
  #pragma unroll
  for (int jt = 0; jt < 4; jt++){
    int crow = jt * 16 + r16;                // bucket index (A row)
    bf16x8 a0, a1;
    #pragma unroll
    for (int e = 0; e < 8; e++){ a0[e] = 0; a1[e] = 0; }
    if (crow < 49){
      const float* rr = rpe + crow * 64 + g * 8;
      float4 x0 = *(const float4*)(rr);
      float4 x1 = *(const float4*)(rr + 4);
      float4 y0 = *(const float4*)(rr + 32);
      float4 y1 = *(const float4*)(rr + 36);
      a0[0]=f2bf(x0.x); a0[1]=f2bf(x0.y); a0[2]=f2bf(x0.z); a0[3]=f2bf(x0.w);
      a0[4]=f2bf(x1.x); a0[5]=f2bf(x1.y); a0[6]=f2bf(x1.z); a0[7]=f2bf(x1.w);
      a1[0]=f2bf(y0.x); a1[1]=f2bf(y0.y); a1[2]=f2bf(y0.z); a1[3]=f2bf(y0.w);
      a1[4]=f2bf(y1.x); a1[5]=f2bf(y1.y); a1[6]=f2bf(y1.z); a1[7]=f2bf(y1.w);
    }
    #pragma unroll
    for (int h = 0; h < 2; h++){
      f32x4 z = {0.f, 0.f, 0.f, 0.f};
      z = mfma16(a0, qf[2 * h], z);
      z = mfma16(a1, qf[2 * h + 1], z);
      int irow = iw + h * 16 + r16;
      uint2 u; u.x = cvt_pk_bf16(z[0], z[1]); u.y = cvt_pk_bf16(z[2], z[3]);
      *(uint2*)(bias_lds + irow * 128 + ((jt * 32 + 8 * g) ^ ((r16 & 7) << 4))) = u;
    }
  }
  const char* brow0 = bias_lds + (iw + r16) * 128;
  const char* brow1 = brow0 + 16 * 128;

  unsigned short* ks = (unsigned short*)smem;
  unsigned short* vs = (unsigned short*)(smem + 8192);
  char* pbuf = smem + 16384 + w * 2048;

  // loop-carried staging pointers (per-thread)
  const int ci0 = tid, ci1 = 256 + tid;
  const int row0 = ci0 >> 3, sc0 = (ci0 & 7) ^ (row0 & 7);
  const int row1 = ci1 >> 3, sc1 = (ci1 & 7) ^ (row1 & 7);
  const char* kp0 = (const char*)(k_s + bh_base) + row0 * 128 + sc0 * 16;
  const char* kp1 = (const char*)(k_s + bh_base) + row1 * 128 + sc1 * 16;
  const char* vp0 = (const char*)(v_t + bh_base) + row0 * 2048 + sc0 * 16;
  const char* vp1 = (const char*)(v_t + bh_base) + row1 * 2048 + sc1 * 16;
  char* kl0 = (char*)smem + w * 1024;
  char* kl1 = (char*)smem + 4096 + w * 1024;
  char* vl0 = (char*)smem + 8192 + w * 1024;
  char* vl1 = (char*)smem + 12288 + w * 1024;
  const unsigned char* rprow0 = rp8 + ((size_t)(qb * 128 + iw + r16) << 10);
  const unsigned char* rprow1 = rprow0 + (16 << 10);

  f32x4 o[8];   // [h*4+dt]
  #pragma unroll
  for (int t = 0; t < 8; t++){ o[t][0]=0.f; o[t][1]=0.f; o[t][2]=0.f; o[t][3]=0.f; }
  float m0 = -INFINITY, m1 = -INFINITY, l0 = 0.f, l1 = 0.f;

  for (int kb = 0; kb < 16; kb++){
    __syncthreads();
    gload_lds16(kp0, kl0);
    gload_lds16(kp1, kl1);
    gload_lds16(vp0, vl0);
    gload_lds16(vp1, vl1);
    kp0 += 8192; kp1 += 8192; vp0 += 128; vp1 += 128;
    __syncthreads();

    // S^T = K . Q^T : st_h[jt][r] = S[row_h][j = kb*64 + 16jt + 4g + r]
    // ka fragments read ONCE, used by both halves.
    f32x4 st0[4], st1[4];
    #pragma unroll
    for (int jt = 0; jt < 4; jt++){
      int krow = jt * 16 + r16;
      int sw = (krow & 7) << 4;
      bf16x8 ka0 = *(const bf16x8*)((char*)ks + krow * 128 + ((g * 16) ^ sw));
      bf16x8 ka1 = *(const bf16x8*)((char*)ks + krow * 128 + ((64 + g * 16) ^ sw));
      f32x4 z0 = {0.f, 0.f, 0.f, 0.f};
      z0 = mfma16(ka0, qf[0], z0);
      z0 = mfma16(ka1, qf[1], z0);
      st0[jt] = z0;
      f32x4 z1 = {0.f, 0.f, 0.f, 0.f};
      z1 = mfma16(ka0, qf[2], z1);
      z1 = mfma16(ka1, qf[3], z1);
      st1[jt] = z1;
    }
    // relative-position bias gather (pre-swizzled byte offsets, bf16 table)
    #pragma unroll
    for (int jt = 0; jt < 4; jt++){
      unsigned bu0 = *(const unsigned*)(rprow0 + kb * 64 + jt * 16 + g * 4);
      unsigned bu1 = *(const unsigned*)(rprow1 + kb * 64 + jt * 16 + g * 4);
      st0[jt][0] += __uint_as_float((unsigned)*(const unsigned short*)(brow0 + (bu0 & 0xff)) << 16);
      st0[jt][1] += __uint_as_float((unsigned)*(const unsigned short*)(brow0 + ((bu0 >> 8) & 0xff)) << 16);
      st0[jt][2] += __uint_as_float((unsigned)*(const unsigned short*)(brow0 + ((bu0 >> 16) & 0xff)) << 16);
      st0[jt][3] += __uint_as_float((unsigned)*(const unsigned short*)(brow0 + (bu0 >> 24)) << 16);
      st1[jt][0] += __uint_as_float((unsigned)*(const unsigned short*)(brow1 + (bu1 & 0xff)) << 16);
      st1[jt][1] += __uint_as_float((unsigned)*(const unsigned short*)(brow1 + ((bu1 >> 8) & 0xff)) << 16);
      st1[jt][2] += __uint_as_float((unsigned)*(const unsigned short*)(brow1 + ((bu1 >> 16) & 0xff)) << 16);
      st1[jt][3] += __uint_as_float((unsigned)*(const unsigned short*)(brow1 + (bu1 >> 24)) << 16);
    }
    // online softmax, exp2 domain (row stats in lanes sharing r16)
    float t0 = -INFINITY, t1 = -INFINITY;
    #pragma unroll
    for (int jt = 0; jt < 4; jt++){
      t0 = fmaxf(t0, fmaxf(fmaxf(st0[jt][0], st0[jt][1]), fmaxf(st0[jt][2], st0[jt][3])));
      t1 = fmaxf(t1, fmaxf(fmaxf(st1[jt][0], st1[jt][1]), fmaxf(st1[jt][2], st1[jt][3])));
    }
    t0 = fmaxf(t0, __shfl_xor(t0, 16)); t0 = fmaxf(t0, __shfl_xor(t0, 32));
    t1 = fmaxf(t1, __shfl_xor(t1, 16)); t1 = fmaxf(t1, __shfl_xor(t1, 32));
    const bool skip = __all(t0 <= m0 + 8.f && t1 <= m1 + 8.f);
    if (!skip){
      float m0n = fmaxf(m0, t0), m1n = fmaxf(m1, t1);
      float a0 = exp2_fast(m0 - m0n), a1 = exp2_fast(m1 - m1n);
      m0 = m0n; m1 = m1n;
      l0 *= a0; l1 *= a1;
      float af0[4], af1[4];
      #pragma unroll
      for (int r = 0; r < 4; r++){ af0[r] = __shfl(a0, 4 * g + r); af1[r] = __shfl(a1, 4 * g + r); }
      #pragma unroll
      for (int dt = 0; dt < 4; dt++){
        o[dt][0] *= af0[0]; o[dt][1] *= af0[1]; o[dt][2] *= af0[2]; o[dt][3] *= af0[3];
        o[4+dt][0] *= af1[0]; o[4+dt][1] *= af1[1]; o[4+dt][2] *= af1[2]; o[4+dt][3] *= af1[3];
      }
    }
    // ---- half 0: P pack -> pbuf, PV ----
    #pragma unroll
    for (int jt = 0; jt < 4; jt++){
      float p0 = exp2_fast(st0[jt][0] - m0);
      float p1 = exp2_fast(st0[jt][1] - m0);
      float p2 = exp2_fast(st0[jt][2] - m0);
      float p3 = exp2_fast(st0[jt][3] - m0);
      l0 += (p0 + p1) + (p2 + p3);
      uint2 u; u.x = cvt_pk_bf16(p0, p1); u.y = cvt_pk_bf16(p2, p3);
      *(uint2*)(pbuf + r16 * 128 + ((jt * 32 + g * 8) ^ ((r16 & 7) << 4))) = u;
    }
    #pragma unroll
    for (int kt = 0; kt < 2; kt++){
      bf16x8 pa = *(const bf16x8*)(pbuf + r16 * 128 + ((kt * 64 + g * 16) ^ ((r16 & 7) << 4)));
      #pragma unroll
      for (int dt = 0; dt < 4; dt++){
        int vrow = dt * 16 + r16;
        bf16x8 vb = *(const bf16x8*)((char*)vs + vrow * 128 + ((kt * 64 + g * 16) ^ ((vrow & 7) << 4)));
        o[dt] = mfma16(pa, vb, o[dt]);
      }
    }
    // ---- half 1: P pack -> same pbuf (wave-private; HW orders DS ops), PV --
    #pragma unroll
    for (int jt = 0; jt < 4; jt++){
      float p0 = exp2_fast(st1[jt][0] - m1);
      float p1 = exp2_fast(st1[jt][1] - m1);
      float p2 = exp2_fast(st1[jt][2] - m1);
      float p3 = exp2_fast(st1[jt][3] - m1);
      l1 += (p0 + p1) + (p2 + p3);
      uint2 u; u.x = cvt_pk_bf16(p0, p1); u.y = cvt_pk_bf16(p2, p3);
      *(uint2*)(pbuf + r16 * 128 + ((jt * 32 + g * 8) ^ ((r16 & 7) << 4))) = u;
    }
    #pragma unroll
    for (int kt = 0; kt < 2; kt++){
      bf16x8 pa = *(const bf16x8*)(pbuf + r16 * 128 + ((kt * 64 + g * 16) ^ ((r16 & 7) << 4)));
      #pragma unroll
      for (int dt = 0; dt < 4; dt++){
        int vrow = dt * 16 + r16;
        bf16x8 vb = *(const bf16x8*)((char*)vs + vrow * 128 + ((kt * 64 + g * 16) ^ ((vrow & 7) << 4)));
        o[4+dt] = mfma16(pa, vb, o[4+dt]);
      }
    }
  }

  // finalize: reduce l across g, divide, store bf16 to [b, i, h*64+d]
  l0 += __shfl_xor(l0, 16); l0 += __shfl_xor(l0, 32);
  l1 += __shfl_xor(l1, 16); l1 += __shfl_xor(l1, 32);
  float lf0[4], lf1[4];
  #pragma unroll
  for (int r = 0; r < 4; r++){
    lf0[r] = 1.f / __shfl(l0, 4 * g + r);
    lf1[r] = 1.f / __shfl(l1, 4 * g + r);
  }
  const int bidx = bh / 12, hh = bh - bidx * 12;
  #pragma unroll
  for (int h = 0; h < 2; h++){
    #pragma unroll
    for (int dt = 0; dt < 4; dt++){
      int d = dt * 16 + r16;
      #pragma unroll
      for (int r = 0; r < 4; r++){
        int i = qb * 128 + iw + h * 16 + 4 * g + r;
        float val = o[h * 4 + dt][r] * (h ? lf1[r] : lf0[r]);
        ao[(size_t)(bidx * 1024 + i) * 768 + hh * 64 + d] = f2bf(val);
      }
    }
  }
}

// ---------------------------------------------------------------------------
// Output projection: out = attn_out @ proj_w^T + proj_b  (f32 out)
// ---------------------------------------------------------------------------
__global__ __launch_bounds__(256) void proj_gemm(
    const unsigned short* __restrict__ aob, const unsigned short* __restrict__ pwb,
    const float* __restrict__ pb, float* __restrict__ out){
  __shared__ __align__(16) unsigned short As[128 * 32];
  __shared__ __align__(16) unsigned short Bs[128 * 32];
  f32x4 acc[4][4];
  #pragma unroll
  for (int i = 0; i < 4; i++)
    #pragma unroll
    for (int j = 0; j < 4; j++){
      acc[i][j][0] = 0.f; acc[i][j][1] = 0.f; acc[i][j][2] = 0.f; acc[i][j][3] = 0.f;
    }
  const int m0 = blockIdx.y * 128, n0 = blockIdx.x * 128;
  gemm_core(aob, pwb, m0, n0, 768, As, Bs, acc);

  const int lane = threadIdx.x & 63, wave = threadIdx.x >> 6;
  const int g = lane >> 4, r16 = lane & 15;
  const int wr = wave >> 1, wc = wave & 1;
  #pragma unroll
  for (int mi = 0; mi < 4; mi++){
    #pragma unroll
    for (int ni = 0; ni < 4; ni++){
      int gcol = n0 + wc * 64 + ni * 16 + r16;
      float bias = pb[gcol];
      #pragma unroll
      for (int r = 0; r < 4; r++){
        int grow = m0 + wr * 64 + mi * 16 + 4 * g + r;
        out[(size_t)grow * 768 + gcol] = acc[mi][ni][r] + bias;
      }
    }
  }
}

// ---------------------------------------------------------------------------
extern "C" void kernel_launch(void* const* d_in, const int* in_sizes, int n_in,
                              void* d_out, int out_size, void* d_ws, size_t ws_size,
                              hipStream_t stream){
  const float* x      = (const float*)d_in[0];
  const float* qkv_w  = (const float*)d_in[1];
  const float* rpe    = (const float*)d_in[2];
  const int*   rp     = (const int*)d_in[3];
  const float* proj_w = (const float*)d_in[4];
  const float* proj_b = (const float*)d_in[5];
  float* out = (float*)d_out;
  char* ws = (char*)d_ws;

  unsigned short* xb  = (unsigned short*)(ws);               // 25,165,824 B
  unsigned short* wb  = (unsigned short*)(ws + 25165824);    //  3,538,944 B
  unsigned short* pwb = (unsigned short*)(ws + 28704768);    //  1,179,648 B
  unsigned char*  rp8 = (unsigned char*) (ws + 29884416);    //  1,048,576 B
  unsigned short* q_s = (unsigned short*)(ws + 30932992);    // 25,165,824 B
  unsigned short* k_s = (unsigned short*)(ws + 56098816);    // 25,165,824 B
  unsigned short* v_t = (unsigned short*)(ws + 81264640);    // 25,165,824 B
  unsigned short* aob = (unsigned short*)(ws + 106430464);   // 25,165,824 B -> 131,596,288 total

  prep_kernel<<<2048, 256, 0, stream>>>(x, qkv_w, proj_w, rp, xb, wb, pwb, rp8);
  qkv_gemm<<<dim3(18, 128), 256, 0, stream>>>(xb, wb, q_s, k_s, v_t);
  attn_kernel<<<dim3(8, 192), 256, 0, stream>>>(q_s, k_s, v_t, rp8, rpe, aob);
  proj_gemm<<<dim3(6, 128), 256, 0, stream>>>(aob, pwb, proj_b, out);
}

// Round 13
// 299.573 us; speedup vs baseline: 1.5047x; 1.0491x over previous
//
#include <hip/hip_runtime.h>

typedef short bf16x8 __attribute__((ext_vector_type(8)));
typedef float f32x4 __attribute__((ext_vector_type(4)));

// Problem constants
// B=16, N=1024, D=768, H=12, HD=64, NUM_BUCKETS=49, SCALE=0.125
// Q is pre-scaled by SCALE*log2(e) so softmax runs in exp2 domain.
#define QSCALE 0.1803368801111204f

__device__ __forceinline__ unsigned short f2bf(float f){
  unsigned u = __float_as_uint(f);
  u = (u + 0x7fffu + ((u >> 16) & 1u)) >> 16;   // round-nearest-even
  return (unsigned short)u;
}
__device__ __forceinline__ f32x4 mfma16(bf16x8 a, bf16x8 b, f32x4 c){
  return __builtin_amdgcn_mfma_f32_16x16x32_bf16(a, b, c, 0, 0, 0);
}
__device__ __forceinline__ void gload_lds16(const void* g, void* l){
  __builtin_amdgcn_global_load_lds((__attribute__((address_space(1))) void*)(g),
                                   (__attribute__((address_space(3))) void*)(l), 16, 0, 0);
}
__device__ __forceinline__ unsigned cvt_pk_bf16(float lo, float hi){
  unsigned r;
  asm("v_cvt_pk_bf16_f32 %0, %1, %2" : "=v"(r) : "v"(lo), "v"(hi));
  return r;
}
// v_exp_f32 computes 2^x natively on gfx950 (cdna4_isa §3)
__device__ __forceinline__ float exp2_fast(float x){
  float r;
  asm("v_exp_f32 %0, %1" : "=v"(r) : "v"(x));
  return r;
}

// ---------------------------------------------------------------------------
// prep: f32 -> bf16 conversions + rp_bucket -> pre-swizzled byte offsets
// rp8[i][j] = (bucket*2) ^ ((i&7)<<4)  (byte offset into swizzled bf16 bias row)
// ---------------------------------------------------------------------------
__global__ __launch_bounds__(256) void prep_kernel(
    const float* __restrict__ x, const float* __restrict__ qw,
    const float* __restrict__ pw, const int* __restrict__ rp,
    unsigned short* __restrict__ xb, unsigned short* __restrict__ wb,
    unsigned short* __restrict__ pwb, unsigned char* __restrict__ rp8){
  const int T1 = 3145728;            // 16384*768/4
  const int T2 = T1 + 442368;        // + 2304*768/4
  const int T3 = T2 + 147456;        // + 768*768/4
  const int T4 = T3 + 262144;        // + 1024*1024/4
  for (int t = blockIdx.x * 256 + threadIdx.x; t < T4; t += gridDim.x * 256){
    if (t < T3){
      const float4* src; ushort4* dst; int off;
      if (t < T1){ src = (const float4*)x;  dst = (ushort4*)xb;  off = t; }
      else if (t < T2){ src = (const float4*)qw; dst = (ushort4*)wb;  off = t - T1; }
      else { src = (const float4*)pw; dst = (ushort4*)pwb; off = t - T2; }
      float4 v = src[off];
      ushort4 u;
      u.x = f2bf(v.x); u.y = f2bf(v.y); u.z = f2bf(v.z); u.w = f2bf(v.w);
      dst[off] = u;
    } else {
      int off = t - T3;
      int4 v = ((const int4*)rp)[off];
      int row = (off * 4) >> 10;               // all 4 j's share the row
      int sw = (row & 7) << 4;
      uchar4 u;
      u.x = (unsigned char)((v.x << 1) ^ sw);
      u.y = (unsigned char)((v.y << 1) ^ sw);
      u.z = (unsigned char)((v.z << 1) ^ sw);
      u.w = (unsigned char)((v.w << 1) ^ sw);
      ((uchar4*)rp8)[off] = u;
    }
  }
}

// ---------------------------------------------------------------------------
// Shared NT-GEMM core: C[128x128] tile, A[M][K], B[N][K] both bf16 K-contig.
// m97 structure: BK=32, global_load_lds(16B) staging, 4 waves 2x2.
// OPERANDS SWAPPED in the MFMA (b first): lane (g,r16) reg r then holds
// C[m0+wr*64+mi*16+r16][n0+wc*64+ni*16+4g+r] -> 4 regs = 4 consecutive
// COLUMNS at a fixed row -> vectorized epilogue stores.
// ---------------------------------------------------------------------------
__device__ __forceinline__ void gemm_core(
    const unsigned short* __restrict__ A, const unsigned short* __restrict__ Bm,
    int m0, int n0, int K, unsigned short* As, unsigned short* Bs,
    f32x4 (&acc)[4][4]){
  const int tid = threadIdx.x, lane = tid & 63, wave = tid >> 6;
  const int g = lane >> 4, r16 = lane & 15;
  const int wr = wave >> 1, wc = wave & 1;
  for (int k0 = 0; k0 < K; k0 += 32){
    __syncthreads();
    #pragma unroll
    for (int j = 0; j < 2; j++){
      int ci = j * 256 + tid;          // chunk id, 512 chunks of 16B per tile
      int row = ci >> 2, c = ci & 3;   // 4 chunks (64B) per row
      gload_lds16(A  + (size_t)(m0 + row) * K + k0 + c * 8,
                  (char*)As + (j * 256 + wave * 64) * 16);
      gload_lds16(Bm + (size_t)(n0 + row) * K + k0 + c * 8,
                  (char*)Bs + (j * 256 + wave * 64) * 16);
    }
    __syncthreads();
    bf16x8 a[4], b[4];
    #pragma unroll
    for (int mi = 0; mi < 4; mi++)
      a[mi] = *(const bf16x8*)((const char*)As + (wr * 64 + mi * 16 + r16) * 64 + g * 16);
    #pragma unroll
    for (int ni = 0; ni < 4; ni++)
      b[ni] = *(const bf16x8*)((const char*)Bs + (wc * 64 + ni * 16 + r16) * 64 + g * 16);
    #pragma unroll
    for (int mi = 0; mi < 4; mi++)
      #pragma unroll
      for (int ni = 0; ni < 4; ni++)
        acc[mi][ni] = mfma16(b[ni], a[mi], acc[mi][ni]);   // swapped
  }
}

// ---------------------------------------------------------------------------
// QKV projection: qkv = x @ qkv_w^T ; route to Q(*QSCALE)[B,H,N,HD],
// K[B,H,N,HD], V^T[B,H,HD,N], all bf16. Each 128-wide n-tile lies wholly in
// one of Q/K/V (768 = 6 x 128) -> sel is block-uniform. Q/K: ushort4 stores.
// ---------------------------------------------------------------------------
__global__ __launch_bounds__(256) void qkv_gemm(
    const unsigned short* __restrict__ xb, const unsigned short* __restrict__ wb,
    unsigned short* __restrict__ q_s, unsigned short* __restrict__ k_s,
    unsigned short* __restrict__ v_t){
  __shared__ __align__(16) unsigned short As[128 * 32];
  __shared__ __align__(16) unsigned short Bs[128 * 32];
  f32x4 acc[4][4];
  #pragma unroll
  for (int i = 0; i < 4; i++)
    #pragma unroll
    for (int j = 0; j < 4; j++){
      acc[i][j][0] = 0.f; acc[i][j][1] = 0.f; acc[i][j][2] = 0.f; acc[i][j][3] = 0.f;
    }
  const int m0 = blockIdx.y * 128, n0 = blockIdx.x * 128;
  gemm_core(xb, wb, m0, n0, 768, As, Bs, acc);

  const int lane = threadIdx.x & 63, wave = threadIdx.x >> 6;
  const int g = lane >> 4, r16 = lane & 15;
  const int wr = wave >> 1, wc = wave & 1;
  const int sel = n0 / 768;                       // block-uniform
  #pragma unroll
  for (int mi = 0; mi < 4; mi++){
    int grow = m0 + wr * 64 + mi * 16 + r16;      // 0..16383 = [16][1024]
    int bb = grow >> 10, ii = grow & 1023;
    #pragma unroll
    for (int ni = 0; ni < 4; ni++){
      int gcol0 = n0 + wc * 64 + ni * 16 + 4 * g; // 4-aligned, never straddles
      int rem = gcol0 - sel * 768;
      int h = rem >> 6, hd0 = rem & 63;
      size_t base = ((size_t)(bb * 12 + h)) << 16;   // *1024*64
      f32x4 v = acc[mi][ni];
      if (sel == 0){
        ushort4 u;
        u.x = f2bf(v[0] * QSCALE); u.y = f2bf(v[1] * QSCALE);
        u.z = f2bf(v[2] * QSCALE); u.w = f2bf(v[3] * QSCALE);
        *(ushort4*)(q_s + base + ((size_t)ii << 6) + hd0) = u;
      } else if (sel == 1){
        ushort4 u;
        u.x = f2bf(v[0]); u.y = f2bf(v[1]); u.z = f2bf(v[2]); u.w = f2bf(v[3]);
        *(ushort4*)(k_s + base + ((size_t)ii << 6) + hd0) = u;
      } else {
        #pragma unroll
        for (int r = 0; r < 4; r++)
          v_t[base + ((size_t)(hd0 + r) << 10) + ii] = f2bf(v[r]);
      }
    }
  }
}

// ---------------------------------------------------------------------------
// Flash attention with relative-position bias (exp2-domain online softmax,
// defer-max THR=8, pre-swizzled bucket byte offsets, bf16 bias table).
// R7 champion: 64 q-rows/block, 4 waves x 16 rows, LDS 32768 B.
// ---------------------------------------------------------------------------
__global__ __launch_bounds__(256) void attn_kernel(
    const unsigned short* __restrict__ q_s, const unsigned short* __restrict__ k_s,
    const unsigned short* __restrict__ v_t, const unsigned char* __restrict__ rp8,
    const float* __restrict__ rpe, unsigned short* __restrict__ ao){
  // LDS layout (32768 B):
  //   [0,8192)      ks  : K tile [64 j][64 hd] bf16, XOR-swizzled
  //   [8192,16384)  vs  : V^T tile [64 d][64 j] bf16, XOR-swizzled
  //   [16384,24576) pbuf: per-wave P [16 i][64 j] bf16, XOR-swizzled
  //   [24576,32768) bias: [64 row][64 bucket] bf16, byte (c*2)^((row&7)<<4)
  __shared__ __align__(16) char smem[32768];
  const int tid = threadIdx.x, lane = tid & 63, w = tid >> 6;
  const int g = lane >> 4, r16 = lane & 15;
  const int qb = blockIdx.x, bh = blockIdx.y;
  const size_t bh_base = (size_t)bh << 16;   // *1024*64 elements

  // ---- Q fragments (B-operand): lane holds Q[i_loc][kc*32 + 8g .. +7] ----
  const int i_loc = w * 16 + r16;
  const size_t qoff = bh_base + ((size_t)(qb * 64 + i_loc) << 6);
  bf16x8 qf0 = *(const bf16x8*)(q_s + qoff + g * 8);
  bf16x8 qf1 = *(const bf16x8*)(q_s + qoff + 32 + g * 8);

  // ---- bias[i][c] = q_i . rpe_c via MFMA; bf16, swizzled; wave-private ----
  char* bias_lds = smem + 24576;
  const int s16 = (r16 & 7) << 4;            // byte-unit row swizzle
  #pragma unroll
  for (int jt = 0; jt < 4; jt++){
    int crow = jt * 16 + r16;                // bucket index (A row)
    bf16x8 a0, a1;
    #pragma unroll
    for (int e = 0; e < 8; e++){ a0[e] = 0; a1[e] = 0; }
    if (crow < 49){
      const float* rr = rpe + crow * 64 + g * 8;
      float4 x0 = *(const float4*)(rr);
      float4 x1 = *(const float4*)(rr + 4);
      float4 y0 = *(const float4*)(rr + 32);
      float4 y1 = *(const float4*)(rr + 36);
      a0[0]=f2bf(x0.x); a0[1]=f2bf(x0.y); a0[2]=f2bf(x0.z); a0[3]=f2bf(x0.w);
      a0[4]=f2bf(x1.x); a0[5]=f2bf(x1.y); a0[6]=f2bf(x1.z); a0[7]=f2bf(x1.w);
      a1[0]=f2bf(y0.x); a1[1]=f2bf(y0.y); a1[2]=f2bf(y0.z); a1[3]=f2bf(y0.w);
      a1[4]=f2bf(y1.x); a1[5]=f2bf(y1.y); a1[6]=f2bf(y1.z); a1[7]=f2bf(y1.w);
    }
    f32x4 z = {0.f, 0.f, 0.f, 0.f};
    z = mfma16(a0, qf0, z);
    z = mfma16(a1, qf1, z);
    uint2 u; u.x = cvt_pk_bf16(z[0], z[1]); u.y = cvt_pk_bf16(z[2], z[3]);
    *(uint2*)(bias_lds + i_loc * 128 + ((jt * 32 + 8 * g) ^ s16)) = u;
  }

  unsigned short* ks = (unsigned short*)smem;
  unsigned short* vs = (unsigned short*)(smem + 8192);
  char* pbuf = smem + 16384 + w * 2048;
  const char* browb = bias_lds + i_loc * 128;

  // loop-carried staging pointers (per-thread)
  const int ci0 = tid, ci1 = 256 + tid;
  const int row0 = ci0 >> 3, sc0 = (ci0 & 7) ^ (row0 & 7);
  const int row1 = ci1 >> 3, sc1 = (ci1 & 7) ^ (row1 & 7);
  const char* kp0 = (const char*)(k_s + bh_base) + row0 * 128 + sc0 * 16;
  const char* kp1 = (const char*)(k_s + bh_base) + row1 * 128 + sc1 * 16;
  const char* vp0 = (const char*)(v_t + bh_base) + row0 * 2048 + sc0 * 16;
  const char* vp1 = (const char*)(v_t + bh_base) + row1 * 2048 + sc1 * 16;
  char* kl0 = (char*)smem + w * 1024;
  char* kl1 = (char*)smem + 4096 + w * 1024;
  char* vl0 = (char*)smem + 8192 + w * 1024;
  char* vl1 = (char*)smem + 12288 + w * 1024;
  const unsigned char* rprow = rp8 + ((size_t)(qb * 64 + i_loc) << 10);

  f32x4 o[4];
  #pragma unroll
  for (int dt = 0; dt < 4; dt++){ o[dt][0]=0.f; o[dt][1]=0.f; o[dt][2]=0.f; o[dt][3]=0.f; }
  float m_i = -INFINITY, l_i = 0.f;

  for (int kb = 0; kb < 16; kb++){
    __syncthreads();
    gload_lds16(kp0, kl0);
    gload_lds16(kp1, kl1);
    gload_lds16(vp0, vl0);
    gload_lds16(vp1, vl1);
    kp0 += 8192; kp1 += 8192; vp0 += 128; vp1 += 128;
    __syncthreads();

    // S^T = K . Q^T : lane holds S[i_loc][j = kb*64 + 16jt + 4g + r]
    f32x4 st[4];
    #pragma unroll
    for (int jt = 0; jt < 4; jt++){
      int krow = jt * 16 + r16;
      int sw = (krow & 7) << 4;
      bf16x8 ka0 = *(const bf16x8*)((char*)ks + krow * 128 + ((g * 16) ^ sw));
      bf16x8 ka1 = *(const bf16x8*)((char*)ks + krow * 128 + ((64 + g * 16) ^ sw));
      f32x4 z = {0.f, 0.f, 0.f, 0.f};
      z = mfma16(ka0, qf0, z);
      z = mfma16(ka1, qf1, z);
      st[jt] = z;
    }
    // relative-position bias gather (pre-swizzled byte offsets, bf16 table)
    #pragma unroll
    for (int jt = 0; jt < 4; jt++){
      unsigned bu = *(const unsigned*)(rprow + kb * 64 + jt * 16 + g * 4);
      st[jt][0] += __uint_as_float((unsigned)*(const unsigned short*)(browb + (bu & 0xff)) << 16);
      st[jt][1] += __uint_as_float((unsigned)*(const unsigned short*)(browb + ((bu >> 8) & 0xff)) << 16);
      st[jt][2] += __uint_as_float((unsigned)*(const unsigned short*)(browb + ((bu >> 16) & 0xff)) << 16);
      st[jt][3] += __uint_as_float((unsigned)*(const unsigned short*)(browb + (bu >> 24)) << 16);
    }
    // online softmax, exp2 domain (row stats in lanes sharing r16)
    float tmax = -INFINITY;
    #pragma unroll
    for (int jt = 0; jt < 4; jt++)
      tmax = fmaxf(tmax, fmaxf(fmaxf(st[jt][0], st[jt][1]), fmaxf(st[jt][2], st[jt][3])));
    tmax = fmaxf(tmax, __shfl_xor(tmax, 16));
    tmax = fmaxf(tmax, __shfl_xor(tmax, 32));
    const bool skip = __all(tmax <= m_i + 8.f);   // defer-max: P bounded by 2^8
    if (!skip){
      float mnew = fmaxf(m_i, tmax);
      float alpha = exp2_fast(m_i - mnew);
      m_i = mnew;
      l_i *= alpha;
      float af[4];
      #pragma unroll
      for (int r = 0; r < 4; r++) af[r] = __shfl(alpha, 4 * g + r);
      #pragma unroll
      for (int dt = 0; dt < 4; dt++){
        o[dt][0] *= af[0]; o[dt][1] *= af[1]; o[dt][2] *= af[2]; o[dt][3] *= af[3];
      }
    }
    // P = exp2(S - m), lane-partial l accumulate, pack to pbuf
    #pragma unroll
    for (int jt = 0; jt < 4; jt++){
      float p0 = exp2_fast(st[jt][0] - m_i);
      float p1 = exp2_fast(st[jt][1] - m_i);
      float p2 = exp2_fast(st[jt][2] - m_i);
      float p3 = exp2_fast(st[jt][3] - m_i);
      l_i += (p0 + p1) + (p2 + p3);
      uint2 u; u.x = cvt_pk_bf16(p0, p1); u.y = cvt_pk_bf16(p2, p3);
      *(uint2*)(pbuf + r16 * 128 + ((jt * 32 + g * 8) ^ ((r16 & 7) << 4))) = u;
    }
    // O += P . V  (A = P from per-wave LDS, B = V^T rows = contiguous j)
    #pragma unroll
    for (int kt = 0; kt < 2; kt++){
      bf16x8 pa = *(const bf16x8*)(pbuf + r16 * 128 + ((kt * 64 + g * 16) ^ ((r16 & 7) << 4)));
      #pragma unroll
      for (int dt = 0; dt < 4; dt++){
        int vrow = dt * 16 + r16;
        bf16x8 vb = *(const bf16x8*)((char*)vs + vrow * 128 + ((kt * 64 + g * 16) ^ ((vrow & 7) << 4)));
        o[dt] = mfma16(pa, vb, o[dt]);
      }
    }
  }

  // finalize: reduce l across g, divide by l, store bf16 to [b, i, h*64+d]
  l_i += __shfl_xor(l_i, 16);
  l_i += __shfl_xor(l_i, 32);
  float lf[4];
  #pragma unroll
  for (int r = 0; r < 4; r++) lf[r] = 1.f / __shfl(l_i, 4 * g + r);
  const int bidx = bh / 12, h = bh - bidx * 12;
  #pragma unroll
  for (int dt = 0; dt < 4; dt++){
    int d = dt * 16 + r16;
    #pragma unroll
    for (int r = 0; r < 4; r++){
      int i = qb * 64 + w * 16 + 4 * g + r;
      ao[(size_t)(bidx * 1024 + i) * 768 + h * 64 + d] = f2bf(o[dt][r] * lf[r]);
    }
  }
}

// ---------------------------------------------------------------------------
// Output projection: out = attn_out @ proj_w^T + proj_b  (f32 out)
// Swapped-operand fragment -> float4 stores with float4 bias loads.
// ---------------------------------------------------------------------------
__global__ __launch_bounds__(256) void proj_gemm(
    const unsigned short* __restrict__ aob, const unsigned short* __restrict__ pwb,
    const float* __restrict__ pb, float* __restrict__ out){
  __shared__ __align__(16) unsigned short As[128 * 32];
  __shared__ __align__(16) unsigned short Bs[128 * 32];
  f32x4 acc[4][4];
  #pragma unroll
  for (int i = 0; i < 4; i++)
    #pragma unroll
    for (int j = 0; j < 4; j++){
      acc[i][j][0] = 0.f; acc[i][j][1] = 0.f; acc[i][j][2] = 0.f; acc[i][j][3] = 0.f;
    }
  const int m0 = blockIdx.y * 128, n0 = blockIdx.x * 128;
  gemm_core(aob, pwb, m0, n0, 768, As, Bs, acc);

  const int lane = threadIdx.x & 63, wave = threadIdx.x >> 6;
  const int g = lane >> 4, r16 = lane & 15;
  const int wr = wave >> 1, wc = wave & 1;
  #pragma unroll
  for (int mi = 0; mi < 4; mi++){
    int grow = m0 + wr * 64 + mi * 16 + r16;
    #pragma unroll
    for (int ni = 0; ni < 4; ni++){
      int gcol0 = n0 + wc * 64 + ni * 16 + 4 * g;
      float4 b4 = *(const float4*)(pb + gcol0);
      f32x4 v = acc[mi][ni];
      float4 ov;
      ov.x = v[0] + b4.x; ov.y = v[1] + b4.y;
      ov.z = v[2] + b4.z; ov.w = v[3] + b4.w;
      *(float4*)(out + (size_t)grow * 768 + gcol0) = ov;
    }
  }
}

// ---------------------------------------------------------------------------
extern "C" void kernel_launch(void* const* d_in, const int* in_sizes, int n_in,
                              void* d_out, int out_size, void* d_ws, size_t ws_size,
                              hipStream_t stream){
  const float* x      = (const float*)d_in[0];
  const float* qkv_w  = (const float*)d_in[1];
  const float* rpe    = (const float*)d_in[2];
  const int*   rp     = (const int*)d_in[3];
  const float* proj_w = (const float*)d_in[4];
  const float* proj_b = (const float*)d_in[5];
  float* out = (float*)d_out;
  char* ws = (char*)d_ws;

  unsigned short* xb  = (unsigned short*)(ws);               // 25,165,824 B
  unsigned short* wb  = (unsigned short*)(ws + 25165824);    //  3,538,944 B
  unsigned short* pwb = (unsigned short*)(ws + 28704768);    //  1,179,648 B
  unsigned char*  rp8 = (unsigned char*) (ws + 29884416);    //  1,048,576 B
  unsigned short* q_s = (unsigned short*)(ws + 30932992);    // 25,165,824 B
  unsigned short* k_s = (unsigned short*)(ws + 56098816);    // 25,165,824 B
  unsigned short* v_t = (unsigned short*)(ws + 81264640);    // 25,165,824 B
  unsigned short* aob = (unsigned short*)(ws + 106430464);   // 25,165,824 B -> 131,596,288 total

  prep_kernel<<<2048, 256, 0, stream>>>(x, qkv_w, proj_w, rp, xb, wb, pwb, rp8);
  qkv_gemm<<<dim3(18, 128), 256, 0, stream>>>(xb, wb, q_s, k_s, v_t);
  attn_kernel<<<dim3(16, 192), 256, 0, stream>>>(q_s, k_s, v_t, rp8, rpe, aob);
  proj_gemm<<<dim3(6, 128), 256, 0, stream>>>(aob, pwb, proj_b, out);
}

// Round 14
// 281.418 us; speedup vs baseline: 1.6018x; 1.0645x over previous
//
#include <hip/hip_runtime.h>

typedef short bf16x8 __attribute__((ext_vector_type(8)));
typedef float f32x4 __attribute__((ext_vector_type(4)));

// Problem constants
// B=16, N=1024, D=768, H=12, HD=64, NUM_BUCKETS=49, SCALE=0.125
// Q is pre-scaled by SCALE*log2(e) so softmax runs in exp2 domain.
#define QSCALE 0.1803368801111204f

__device__ __forceinline__ unsigned short f2bf(float f){
  unsigned u = __float_as_uint(f);
  u = (u + 0x7fffu + ((u >> 16) & 1u)) >> 16;   // round-nearest-even
  return (unsigned short)u;
}
__device__ __forceinline__ f32x4 mfma16(bf16x8 a, bf16x8 b, f32x4 c){
  return __builtin_amdgcn_mfma_f32_16x16x32_bf16(a, b, c, 0, 0, 0);
}
__device__ __forceinline__ void gload_lds16(const void* g, void* l){
  __builtin_amdgcn_global_load_lds((__attribute__((address_space(1))) void*)(g),
                                   (__attribute__((address_space(3))) void*)(l), 16, 0, 0);
}
__device__ __forceinline__ unsigned cvt_pk_bf16(float lo, float hi){
  unsigned r;
  asm("v_cvt_pk_bf16_f32 %0, %1, %2" : "=v"(r) : "v"(lo), "v"(hi));
  return r;
}
// v_exp_f32 computes 2^x natively on gfx950 (cdna4_isa §3)
__device__ __forceinline__ float exp2_fast(float x){
  float r;
  asm("v_exp_f32 %0, %1" : "=v"(r) : "v"(x));
  return r;
}

// ---------------------------------------------------------------------------
// prep: f32 -> bf16 conversions + rp_bucket -> pre-swizzled byte offsets
// ---------------------------------------------------------------------------
__global__ __launch_bounds__(256) void prep_kernel(
    const float* __restrict__ x, const float* __restrict__ qw,
    const float* __restrict__ pw, const int* __restrict__ rp,
    unsigned short* __restrict__ xb, unsigned short* __restrict__ wb,
    unsigned short* __restrict__ pwb, unsigned char* __restrict__ rp8){
  const int T1 = 3145728;            // 16384*768/4
  const int T2 = T1 + 442368;        // + 2304*768/4
  const int T3 = T2 + 147456;        // + 768*768/4
  const int T4 = T3 + 262144;        // + 1024*1024/4
  for (int t = blockIdx.x * 256 + threadIdx.x; t < T4; t += gridDim.x * 256){
    if (t < T3){
      const float4* src; ushort4* dst; int off;
      if (t < T1){ src = (const float4*)x;  dst = (ushort4*)xb;  off = t; }
      else if (t < T2){ src = (const float4*)qw; dst = (ushort4*)wb;  off = t - T1; }
      else { src = (const float4*)pw; dst = (ushort4*)pwb; off = t - T2; }
      float4 v = src[off];
      ushort4 u;
      u.x = f2bf(v.x); u.y = f2bf(v.y); u.z = f2bf(v.z); u.w = f2bf(v.w);
      dst[off] = u;
    } else {
      int off = t - T3;
      int4 v = ((const int4*)rp)[off];
      int row = (off * 4) >> 10;               // all 4 j's share the row
      int sw = (row & 7) << 4;
      uchar4 u;
      u.x = (unsigned char)((v.x << 1) ^ sw);
      u.y = (unsigned char)((v.y << 1) ^ sw);
      u.z = (unsigned char)((v.z << 1) ^ sw);
      u.w = (unsigned char)((v.w << 1) ^ sw);
      ((uchar4*)rp8)[off] = u;
    }
  }
}

// ---------------------------------------------------------------------------
// 256x256 8-phase GEMM core (plain-HIP port of the m201 schedule, BK=32 so
// LDS fits 64KB static). 512 threads = 8 waves (2 wr x 4 wc); per-wave C-tile
// 128x64 = acc[8][4]. NT = K/32 K-tiles; 2 tiles/iteration, 8 phases.
// Counted vmcnt(2) at phase 0/4 only; raw s_barrier x4/iter (no drain-0).
// LDS tile layout: [128 lines][128B], each line = 2 rows of 32 bf16, chunks
// XOR-swizzled by (line&7) (stage source pre-swizzled, read swizzled).
// MFMA operands swapped (b first) -> reg r = consecutive C columns.
// ---------------------------------------------------------------------------
__device__ __forceinline__ void stage_half256(
    const unsigned short* __restrict__ M, int r0, int K, int kt, int half,
    char* dst, int tid){
  int ci = half * 512 + tid;          // chunk id within 16KB tile (1024 chunks)
  int lr = ci >> 3, s = ci & 7;
  int cc = s ^ (lr & 7);
  int grow = lr * 2 + (cc >> 2);
  int gk = (cc & 3) * 8;
  gload_lds16(M + (size_t)(r0 + grow) * K + kt * 32 + gk, dst + ci * 16);
}

__device__ __forceinline__ void gemm_core256(
    const unsigned short* __restrict__ A, const unsigned short* __restrict__ Bm,
    int m0, int n0, int K, char* smem, f32x4 (&acc)[8][4]){
  const int tid = threadIdx.x, lane = tid & 63;
  const int w = tid >> 6, g = lane >> 4, r16 = lane & 15;
  const int wr = w >> 2, wc = w & 3;
  const int NT = K >> 5;
  char* Ab0 = smem;            char* Ab1 = smem + 16384;
  char* Bb0 = smem + 32768;    char* Bb1 = smem + 49152;

  // prologue: B(0), A(0), B(1) -> 6 outstanding loads/thread
  stage_half256(Bm, n0, K, 0, 0, Bb0, tid);
  stage_half256(Bm, n0, K, 0, 1, Bb0, tid);
  stage_half256(A,  m0, K, 0, 0, Ab0, tid);
  stage_half256(A,  m0, K, 0, 1, Ab0, tid);
  stage_half256(Bm, n0, K, 1, 0, Bb1, tid);
  stage_half256(Bm, n0, K, 1, 1, Bb1, tid);

  const int arb = wr * 128 + r16;
  const int brb = wc * 64 + r16;
  bf16x8 bq[4];

#define LOADB_(buf) { \
  _Pragma("unroll") \
  for (int ni = 0; ni < 4; ni++){ \
    int row = brb + ni * 16; int lr = row >> 1; \
    bq[ni] = *(const bf16x8*)((buf) + lr * 128 + ((((row & 1) << 6) + g * 16) ^ ((lr & 7) << 4))); } }
#define QUAD_(buf, p) { \
  int ra = arb + (2 * (p)) * 16; int rb = ra + 16; \
  int la = ra >> 1, lb = rb >> 1; \
  bf16x8 afa = *(const bf16x8*)((buf) + la * 128 + ((((ra & 1) << 6) + g * 16) ^ ((la & 7) << 4))); \
  bf16x8 afb = *(const bf16x8*)((buf) + lb * 128 + ((((rb & 1) << 6) + g * 16) ^ ((lb & 7) << 4))); \
  _Pragma("unroll") \
  for (int ni = 0; ni < 4; ni++){ \
    acc[2 * (p)][ni]     = mfma16(bq[ni], afa, acc[2 * (p)][ni]); \
    acc[2 * (p) + 1][ni] = mfma16(bq[ni], afb, acc[2 * (p) + 1][ni]); } }

  for (int T = 0; T < NT; T += 2){
    int t2 = T + 2, t3 = T + 3;
    if (t2 >= NT) t2 -= NT;
    if (t3 >= NT) t3 -= NT;
    // loop top: B(T),A(T) landed (leave B(T+1) in flight)
    asm volatile("s_waitcnt vmcnt(2) lgkmcnt(0)" ::: "memory");
    __builtin_amdgcn_s_barrier();
    __builtin_amdgcn_sched_barrier(0);
    // ph0
    stage_half256(A, m0, K, T + 1, 0, Ab1, tid);
    LOADB_(Bb0); QUAD_(Ab0, 0);
    // ph1
    stage_half256(A, m0, K, T + 1, 1, Ab1, tid);
    QUAD_(Ab0, 1);
    asm volatile("s_waitcnt lgkmcnt(0)" ::: "memory");
    __builtin_amdgcn_s_barrier();            // frees Bb0 for restage
    __builtin_amdgcn_sched_barrier(0);
    // ph2
    stage_half256(Bm, n0, K, t2, 0, Bb0, tid);
    QUAD_(Ab0, 2);
    // ph3
    stage_half256(Bm, n0, K, t2, 1, Bb0, tid);
    QUAD_(Ab0, 3);
    // B(T+1),A(T+1) landed (leave B(T+2) in flight)
    asm volatile("s_waitcnt vmcnt(2) lgkmcnt(0)" ::: "memory");
    __builtin_amdgcn_s_barrier();
    __builtin_amdgcn_sched_barrier(0);
    // ph4
    stage_half256(A, m0, K, t2, 0, Ab0, tid);
    LOADB_(Bb1); QUAD_(Ab1, 0);
    // ph5
    stage_half256(A, m0, K, t2, 1, Ab0, tid);
    QUAD_(Ab1, 1);
    asm volatile("s_waitcnt lgkmcnt(0)" ::: "memory");
    __builtin_amdgcn_s_barrier();            // frees Bb1 for restage
    __builtin_amdgcn_sched_barrier(0);
    // ph6
    stage_half256(Bm, n0, K, t3, 0, Bb1, tid);
    QUAD_(Ab1, 2);
    // ph7
    stage_half256(Bm, n0, K, t3, 1, Bb1, tid);
    QUAD_(Ab1, 3);
  }
#undef LOADB_
#undef QUAD_
}

// ---------------------------------------------------------------------------
// QKV projection (256² 8-phase): qkv = x @ qkv_w^T ; route to
// Q(*QSCALE)[B,H,N,HD], K[B,H,N,HD], V^T[B,H,HD,N], bf16.
// Each 256-wide n-tile lies wholly in one of Q/K/V (768 = 3 x 256).
// ---------------------------------------------------------------------------
__global__ __launch_bounds__(512, 2) void qkv_gemm(
    const unsigned short* __restrict__ xb, const unsigned short* __restrict__ wb,
    unsigned short* __restrict__ q_s, unsigned short* __restrict__ k_s,
    unsigned short* __restrict__ v_t){
  __shared__ __align__(16) char smem[65536];
  f32x4 acc[8][4];
  #pragma unroll
  for (int i = 0; i < 8; i++)
    #pragma unroll
    for (int j = 0; j < 4; j++){
      acc[i][j][0] = 0.f; acc[i][j][1] = 0.f; acc[i][j][2] = 0.f; acc[i][j][3] = 0.f;
    }
  const int m0 = blockIdx.y * 256, n0 = blockIdx.x * 256;
  gemm_core256(xb, wb, m0, n0, 768, smem, acc);

  const int tid = threadIdx.x, lane = tid & 63, w = tid >> 6;
  const int g = lane >> 4, r16 = lane & 15;
  const int wr = w >> 2, wc = w & 3;
  const int sel = n0 / 768;                       // block-uniform
  #pragma unroll
  for (int mi = 0; mi < 8; mi++){
    int grow = m0 + wr * 128 + mi * 16 + r16;     // 0..16383 = [16][1024]
    int bb = grow >> 10, ii = grow & 1023;
    #pragma unroll
    for (int ni = 0; ni < 4; ni++){
      int gcol0 = n0 + wc * 64 + ni * 16 + 4 * g; // 4-aligned, within one head
      int rem = gcol0 - sel * 768;
      int h = rem >> 6, hd0 = rem & 63;
      size_t base = ((size_t)(bb * 12 + h)) << 16;   // *1024*64
      f32x4 v = acc[mi][ni];
      if (sel == 0){
        ushort4 u;
        u.x = f2bf(v[0] * QSCALE); u.y = f2bf(v[1] * QSCALE);
        u.z = f2bf(v[2] * QSCALE); u.w = f2bf(v[3] * QSCALE);
        *(ushort4*)(q_s + base + ((size_t)ii << 6) + hd0) = u;
      } else if (sel == 1){
        ushort4 u;
        u.x = f2bf(v[0]); u.y = f2bf(v[1]); u.z = f2bf(v[2]); u.w = f2bf(v[3]);
        *(ushort4*)(k_s + base + ((size_t)ii << 6) + hd0) = u;
      } else {
        #pragma unroll
        for (int r = 0; r < 4; r++)
          v_t[base + ((size_t)(hd0 + r) << 10) + ii] = f2bf(v[r]);
      }
    }
  }
}

// ---------------------------------------------------------------------------
// Flash attention with relative-position bias (exp2-domain online softmax,
// defer-max THR=8, pre-swizzled bucket byte offsets, bf16 bias table).
// R7/R13 champion: 64 q-rows/block, 4 waves x 16 rows, LDS 32768 B.
// ---------------------------------------------------------------------------
__global__ __launch_bounds__(256) void attn_kernel(
    const unsigned short* __restrict__ q_s, const unsigned short* __restrict__ k_s,
    const unsigned short* __restrict__ v_t, const unsigned char* __restrict__ rp8,
    const float* __restrict__ rpe, unsigned short* __restrict__ ao){
  __shared__ __align__(16) char smem[32768];
  const int tid = threadIdx.x, lane = tid & 63, w = tid >> 6;
  const int g = lane >> 4, r16 = lane & 15;
  const int qb = blockIdx.x, bh = blockIdx.y;
  const size_t bh_base = (size_t)bh << 16;   // *1024*64 elements

  const int i_loc = w * 16 + r16;
  const size_t qoff = bh_base + ((size_t)(qb * 64 + i_loc) << 6);
  bf16x8 qf0 = *(const bf16x8*)(q_s + qoff + g * 8);
  bf16x8 qf1 = *(const bf16x8*)(q_s + qoff + 32 + g * 8);

  // bias[i][c] = q_i . rpe_c via MFMA; bf16, swizzled; wave-private
  char* bias_lds = smem + 24576;
  const int s16 = (r16 & 7) << 4;
  #pragma unroll
  for (int jt = 0; jt < 4; jt++){
    int crow = jt * 16 + r16;
    bf16x8 a0, a1;
    #pragma unroll
    for (int e = 0; e < 8; e++){ a0[e] = 0; a1[e] = 0; }
    if (crow < 49){
      const float* rr = rpe + crow * 64 + g * 8;
      float4 x0 = *(const float4*)(rr);
      float4 x1 = *(const float4*)(rr + 4);
      float4 y0 = *(const float4*)(rr + 32);
      float4 y1 = *(const float4*)(rr + 36);
      a0[0]=f2bf(x0.x); a0[1]=f2bf(x0.y); a0[2]=f2bf(x0.z); a0[3]=f2bf(x0.w);
      a0[4]=f2bf(x1.x); a0[5]=f2bf(x1.y); a0[6]=f2bf(x1.z); a0[7]=f2bf(x1.w);
      a1[0]=f2bf(y0.x); a1[1]=f2bf(y0.y); a1[2]=f2bf(y0.z); a1[3]=f2bf(y0.w);
      a1[4]=f2bf(y1.x); a1[5]=f2bf(y1.y); a1[6]=f2bf(y1.z); a1[7]=f2bf(y1.w);
    }
    f32x4 z = {0.f, 0.f, 0.f, 0.f};
    z = mfma16(a0, qf0, z);
    z = mfma16(a1, qf1, z);
    uint2 u; u.x = cvt_pk_bf16(z[0], z[1]); u.y = cvt_pk_bf16(z[2], z[3]);
    *(uint2*)(bias_lds + i_loc * 128 + ((jt * 32 + 8 * g) ^ s16)) = u;
  }

  unsigned short* ks = (unsigned short*)smem;
  unsigned short* vs = (unsigned short*)(smem + 8192);
  char* pbuf = smem + 16384 + w * 2048;
  const char* browb = bias_lds + i_loc * 128;

  const int ci0 = tid, ci1 = 256 + tid;
  const int row0 = ci0 >> 3, sc0 = (ci0 & 7) ^ (row0 & 7);
  const int row1 = ci1 >> 3, sc1 = (ci1 & 7) ^ (row1 & 7);
  const char* kp0 = (const char*)(k_s + bh_base) + row0 * 128 + sc0 * 16;
  const char* kp1 = (const char*)(k_s + bh_base) + row1 * 128 + sc1 * 16;
  const char* vp0 = (const char*)(v_t + bh_base) + row0 * 2048 + sc0 * 16;
  const char* vp1 = (const char*)(v_t + bh_base) + row1 * 2048 + sc1 * 16;
  char* kl0 = (char*)smem + w * 1024;
  char* kl1 = (char*)smem + 4096 + w * 1024;
  char* vl0 = (char*)smem + 8192 + w * 1024;
  char* vl1 = (char*)smem + 12288 + w * 1024;
  const unsigned char* rprow = rp8 + ((size_t)(qb * 64 + i_loc) << 10);

  f32x4 o[4];
  #pragma unroll
  for (int dt = 0; dt < 4; dt++){ o[dt][0]=0.f; o[dt][1]=0.f; o[dt][2]=0.f; o[dt][3]=0.f; }
  float m_i = -INFINITY, l_i = 0.f;

  for (int kb = 0; kb < 16; kb++){
    __syncthreads();
    gload_lds16(kp0, kl0);
    gload_lds16(kp1, kl1);
    gload_lds16(vp0, vl0);
    gload_lds16(vp1, vl1);
    kp0 += 8192; kp1 += 8192; vp0 += 128; vp1 += 128;
    __syncthreads();

    f32x4 st[4];
    #pragma unroll
    for (int jt = 0; jt < 4; jt++){
      int krow = jt * 16 + r16;
      int sw = (krow & 7) << 4;
      bf16x8 ka0 = *(const bf16x8*)((char*)ks + krow * 128 + ((g * 16) ^ sw));
      bf16x8 ka1 = *(const bf16x8*)((char*)ks + krow * 128 + ((64 + g * 16) ^ sw));
      f32x4 z = {0.f, 0.f, 0.f, 0.f};
      z = mfma16(ka0, qf0, z);
      z = mfma16(ka1, qf1, z);
      st[jt] = z;
    }
    #pragma unroll
    for (int jt = 0; jt < 4; jt++){
      unsigned bu = *(const unsigned*)(rprow + kb * 64 + jt * 16 + g * 4);
      st[jt][0] += __uint_as_float((unsigned)*(const unsigned short*)(browb + (bu & 0xff)) << 16);
      st[jt][1] += __uint_as_float((unsigned)*(const unsigned short*)(browb + ((bu >> 8) & 0xff)) << 16);
      st[jt][2] += __uint_as_float((unsigned)*(const unsigned short*)(browb + ((bu >> 16) & 0xff)) << 16);
      st[jt][3] += __uint_as_float((unsigned)*(const unsigned short*)(browb + (bu >> 24)) << 16);
    }
    float tmax = -INFINITY;
    #pragma unroll
    for (int jt = 0; jt < 4; jt++)
      tmax = fmaxf(tmax, fmaxf(fmaxf(st[jt][0], st[jt][1]), fmaxf(st[jt][2], st[jt][3])));
    tmax = fmaxf(tmax, __shfl_xor(tmax, 16));
    tmax = fmaxf(tmax, __shfl_xor(tmax, 32));
    const bool skip = __all(tmax <= m_i + 8.f);
    if (!skip){
      float mnew = fmaxf(m_i, tmax);
      float alpha = exp2_fast(m_i - mnew);
      m_i = mnew;
      l_i *= alpha;
      float af[4];
      #pragma unroll
      for (int r = 0; r < 4; r++) af[r] = __shfl(alpha, 4 * g + r);
      #pragma unroll
      for (int dt = 0; dt < 4; dt++){
        o[dt][0] *= af[0]; o[dt][1] *= af[1]; o[dt][2] *= af[2]; o[dt][3] *= af[3];
      }
    }
    #pragma unroll
    for (int jt = 0; jt < 4; jt++){
      float p0 = exp2_fast(st[jt][0] - m_i);
      float p1 = exp2_fast(st[jt][1] - m_i);
      float p2 = exp2_fast(st[jt][2] - m_i);
      float p3 = exp2_fast(st[jt][3] - m_i);
      l_i += (p0 + p1) + (p2 + p3);
      uint2 u; u.x = cvt_pk_bf16(p0, p1); u.y = cvt_pk_bf16(p2, p3);
      *(uint2*)(pbuf + r16 * 128 + ((jt * 32 + g * 8) ^ ((r16 & 7) << 4))) = u;
    }
    #pragma unroll
    for (int kt = 0; kt < 2; kt++){
      bf16x8 pa = *(const bf16x8*)(pbuf + r16 * 128 + ((kt * 64 + g * 16) ^ ((r16 & 7) << 4)));
      #pragma unroll
      for (int dt = 0; dt < 4; dt++){
        int vrow = dt * 16 + r16;
        bf16x8 vb = *(const bf16x8*)((char*)vs + vrow * 128 + ((kt * 64 + g * 16) ^ ((vrow & 7) << 4)));
        o[dt] = mfma16(pa, vb, o[dt]);
      }
    }
  }

  l_i += __shfl_xor(l_i, 16);
  l_i += __shfl_xor(l_i, 32);
  float lf[4];
  #pragma unroll
  for (int r = 0; r < 4; r++) lf[r] = 1.f / __shfl(l_i, 4 * g + r);
  const int bidx = bh / 12, h = bh - bidx * 12;
  #pragma unroll
  for (int dt = 0; dt < 4; dt++){
    int d = dt * 16 + r16;
    #pragma unroll
    for (int r = 0; r < 4; r++){
      int i = qb * 64 + w * 16 + 4 * g + r;
      ao[(size_t)(bidx * 1024 + i) * 768 + h * 64 + d] = f2bf(o[dt][r] * lf[r]);
    }
  }
}

// ---------------------------------------------------------------------------
// Output projection (256² 8-phase): out = attn_out @ proj_w^T + proj_b (f32)
// ---------------------------------------------------------------------------
__global__ __launch_bounds__(512, 2) void proj_gemm(
    const unsigned short* __restrict__ aob, const unsigned short* __restrict__ pwb,
    const float* __restrict__ pb, float* __restrict__ out){
  __shared__ __align__(16) char smem[65536];
  f32x4 acc[8][4];
  #pragma unroll
  for (int i = 0; i < 8; i++)
    #pragma unroll
    for (int j = 0; j < 4; j++){
      acc[i][j][0] = 0.f; acc[i][j][1] = 0.f; acc[i][j][2] = 0.f; acc[i][j][3] = 0.f;
    }
  const int m0 = blockIdx.y * 256, n0 = blockIdx.x * 256;
  gemm_core256(aob, pwb, m0, n0, 768, smem, acc);

  const int tid = threadIdx.x, lane = tid & 63, w = tid >> 6;
  const int g = lane >> 4, r16 = lane & 15;
  const int wr = w >> 2, wc = w & 3;
  #pragma unroll
  for (int mi = 0; mi < 8; mi++){
    int grow = m0 + wr * 128 + mi * 16 + r16;
    #pragma unroll
    for (int ni = 0; ni < 4; ni++){
      int gcol0 = n0 + wc * 64 + ni * 16 + 4 * g;
      float4 b4 = *(const float4*)(pb + gcol0);
      f32x4 v = acc[mi][ni];
      float4 ov;
      ov.x = v[0] + b4.x; ov.y = v[1] + b4.y;
      ov.z = v[2] + b4.z; ov.w = v[3] + b4.w;
      *(float4*)(out + (size_t)grow * 768 + gcol0) = ov;
    }
  }
}

// ---------------------------------------------------------------------------
extern "C" void kernel_launch(void* const* d_in, const int* in_sizes, int n_in,
                              void* d_out, int out_size, void* d_ws, size_t ws_size,
                              hipStream_t stream){
  const float* x      = (const float*)d_in[0];
  const float* qkv_w  = (const float*)d_in[1];
  const float* rpe    = (const float*)d_in[2];
  const int*   rp     = (const int*)d_in[3];
  const float* proj_w = (const float*)d_in[4];
  const float* proj_b = (const float*)d_in[5];
  float* out = (float*)d_out;
  char* ws = (char*)d_ws;

  unsigned short* xb  = (unsigned short*)(ws);               // 25,165,824 B
  unsigned short* wb  = (unsigned short*)(ws + 25165824);    //  3,538,944 B
  unsigned short* pwb = (unsigned short*)(ws + 28704768);    //  1,179,648 B
  unsigned char*  rp8 = (unsigned char*) (ws + 29884416);    //  1,048,576 B
  unsigned short* q_s = (unsigned short*)(ws + 30932992);    // 25,165,824 B
  unsigned short* k_s = (unsigned short*)(ws + 56098816);    // 25,165,824 B
  unsigned short* v_t = (unsigned short*)(ws + 81264640);    // 25,165,824 B
  unsigned short* aob = (unsigned short*)(ws + 106430464);   // 25,165,824 B -> 131,596,288 total

  prep_kernel<<<2048, 256, 0, stream>>>(x, qkv_w, proj_w, rp, xb, wb, pwb, rp8);
  qkv_gemm<<<dim3(9, 64), 512, 0, stream>>>(xb, wb, q_s, k_s, v_t);
  attn_kernel<<<dim3(16, 192), 256, 0, stream>>>(q_s, k_s, v_t, rp8, rpe, aob);
  proj_gemm<<<dim3(3, 64), 512, 0, stream>>>(aob, pwb, proj_b, out);
}

// Round 15
// 279.444 us; speedup vs baseline: 1.6131x; 1.0071x over previous
//
#include <hip/hip_runtime.h>

typedef short bf16x8 __attribute__((ext_vector_type(8)));
typedef float f32x4 __attribute__((ext_vector_type(4)));

// Problem constants
// B=16, N=1024, D=768, H=12, HD=64, NUM_BUCKETS=49, SCALE=0.125
// Q is pre-scaled by SCALE*log2(e) so softmax runs in exp2 domain.
#define QSCALE 0.1803368801111204f

__device__ __forceinline__ unsigned short f2bf(float f){
  unsigned u = __float_as_uint(f);
  u = (u + 0x7fffu + ((u >> 16) & 1u)) >> 16;   // round-nearest-even
  return (unsigned short)u;
}
__device__ __forceinline__ f32x4 mfma16(bf16x8 a, bf16x8 b, f32x4 c){
  return __builtin_amdgcn_mfma_f32_16x16x32_bf16(a, b, c, 0, 0, 0);
}
__device__ __forceinline__ void gload_lds16(const void* g, void* l){
  __builtin_amdgcn_global_load_lds((__attribute__((address_space(1))) void*)(g),
                                   (__attribute__((address_space(3))) void*)(l), 16, 0, 0);
}
__device__ __forceinline__ unsigned cvt_pk_bf16(float lo, float hi){
  unsigned r;
  asm("v_cvt_pk_bf16_f32 %0, %1, %2" : "=v"(r) : "v"(lo), "v"(hi));
  return r;
}
// v_exp_f32 computes 2^x natively on gfx950 (cdna4_isa §3)
__device__ __forceinline__ float exp2_fast(float x){
  float r;
  asm("v_exp_f32 %0, %1" : "=v"(r) : "v"(x));
  return r;
}

// ---------------------------------------------------------------------------
// prep: f32 -> bf16 conversions + rp_bucket -> pre-swizzled byte offsets
// ---------------------------------------------------------------------------
__global__ __launch_bounds__(256) void prep_kernel(
    const float* __restrict__ x, const float* __restrict__ qw,
    const float* __restrict__ pw, const int* __restrict__ rp,
    unsigned short* __restrict__ xb, unsigned short* __restrict__ wb,
    unsigned short* __restrict__ pwb, unsigned char* __restrict__ rp8){
  const int T1 = 3145728;            // 16384*768/4
  const int T2 = T1 + 442368;        // + 2304*768/4
  const int T3 = T2 + 147456;        // + 768*768/4
  const int T4 = T3 + 262144;        // + 1024*1024/4
  for (int t = blockIdx.x * 256 + threadIdx.x; t < T4; t += gridDim.x * 256){
    if (t < T3){
      const float4* src; ushort4* dst; int off;
      if (t < T1){ src = (const float4*)x;  dst = (ushort4*)xb;  off = t; }
      else if (t < T2){ src = (const float4*)qw; dst = (ushort4*)wb;  off = t - T1; }
      else { src = (const float4*)pw; dst = (ushort4*)pwb; off = t - T2; }
      float4 v = src[off];
      ushort4 u;
      u.x = f2bf(v.x); u.y = f2bf(v.y); u.z = f2bf(v.z); u.w = f2bf(v.w);
      dst[off] = u;
    } else {
      int off = t - T3;
      int4 v = ((const int4*)rp)[off];
      int row = (off * 4) >> 10;               // all 4 j's share the row
      int sw = (row & 7) << 4;
      uchar4 u;
      u.x = (unsigned char)((v.x << 1) ^ sw);
      u.y = (unsigned char)((v.y << 1) ^ sw);
      u.z = (unsigned char)((v.z << 1) ^ sw);
      u.w = (unsigned char)((v.w << 1) ^ sw);
      ((uchar4*)rp8)[off] = u;
    }
  }
}

// ---------------------------------------------------------------------------
// 256x256 8-phase GEMM core (plain-HIP port of the m201 schedule, BK=32 so
// LDS fits 64KB static). 512 threads = 8 waves (2 wr x 4 wc); per-wave C-tile
// 128x64 = acc[8][4]. NT = K/32 K-tiles; 2 tiles/iteration, 8 phases.
// Counted vmcnt(2) at phase 0/4 only; raw s_barrier x4/iter (no drain-0).
// T5: s_setprio(1) around each 8-MFMA cluster (m218b: +21-25% on 8-phase).
// LDS tile layout: [128 lines][128B], each line = 2 rows of 32 bf16, chunks
// XOR-swizzled by (line&7) (stage source pre-swizzled, read swizzled).
// MFMA operands swapped (b first) -> reg r = consecutive C columns.
// ---------------------------------------------------------------------------
__device__ __forceinline__ void stage_half256(
    const unsigned short* __restrict__ M, int r0, int K, int kt, int half,
    char* dst, int tid){
  int ci = half * 512 + tid;          // chunk id within 16KB tile (1024 chunks)
  int lr = ci >> 3, s = ci & 7;
  int cc = s ^ (lr & 7);
  int grow = lr * 2 + (cc >> 2);
  int gk = (cc & 3) * 8;
  gload_lds16(M + (size_t)(r0 + grow) * K + kt * 32 + gk, dst + ci * 16);
}

__device__ __forceinline__ void gemm_core256(
    const unsigned short* __restrict__ A, const unsigned short* __restrict__ Bm,
    int m0, int n0, int K, char* smem, f32x4 (&acc)[8][4]){
  const int tid = threadIdx.x, lane = tid & 63;
  const int w = tid >> 6, g = lane >> 4, r16 = lane & 15;
  const int wr = w >> 2, wc = w & 3;
  const int NT = K >> 5;
  char* Ab0 = smem;            char* Ab1 = smem + 16384;
  char* Bb0 = smem + 32768;    char* Bb1 = smem + 49152;

  // prologue: B(0), A(0), B(1) -> 6 outstanding loads/thread
  stage_half256(Bm, n0, K, 0, 0, Bb0, tid);
  stage_half256(Bm, n0, K, 0, 1, Bb0, tid);
  stage_half256(A,  m0, K, 0, 0, Ab0, tid);
  stage_half256(A,  m0, K, 0, 1, Ab0, tid);
  stage_half256(Bm, n0, K, 1, 0, Bb1, tid);
  stage_half256(Bm, n0, K, 1, 1, Bb1, tid);

  const int arb = wr * 128 + r16;
  const int brb = wc * 64 + r16;
  bf16x8 bq[4];

#define LOADB_(buf) { \
  _Pragma("unroll") \
  for (int ni = 0; ni < 4; ni++){ \
    int row = brb + ni * 16; int lr = row >> 1; \
    bq[ni] = *(const bf16x8*)((buf) + lr * 128 + ((((row & 1) << 6) + g * 16) ^ ((lr & 7) << 4))); } }
#define QUAD_(buf, p) { \
  int ra = arb + (2 * (p)) * 16; int rb = ra + 16; \
  int la = ra >> 1, lb = rb >> 1; \
  bf16x8 afa = *(const bf16x8*)((buf) + la * 128 + ((((ra & 1) << 6) + g * 16) ^ ((la & 7) << 4))); \
  bf16x8 afb = *(const bf16x8*)((buf) + lb * 128 + ((((rb & 1) << 6) + g * 16) ^ ((lb & 7) << 4))); \
  __builtin_amdgcn_s_setprio(1); \
  _Pragma("unroll") \
  for (int ni = 0; ni < 4; ni++){ \
    acc[2 * (p)][ni]     = mfma16(bq[ni], afa, acc[2 * (p)][ni]); \
    acc[2 * (p) + 1][ni] = mfma16(bq[ni], afb, acc[2 * (p) + 1][ni]); } \
  __builtin_amdgcn_s_setprio(0); }

  for (int T = 0; T < NT; T += 2){
    int t2 = T + 2, t3 = T + 3;
    if (t2 >= NT) t2 -= NT;
    if (t3 >= NT) t3 -= NT;
    // loop top: B(T),A(T) landed (leave B(T+1) in flight)
    asm volatile("s_waitcnt vmcnt(2) lgkmcnt(0)" ::: "memory");
    __builtin_amdgcn_s_barrier();
    __builtin_amdgcn_sched_barrier(0);
    // ph0
    stage_half256(A, m0, K, T + 1, 0, Ab1, tid);
    LOADB_(Bb0); QUAD_(Ab0, 0);
    // ph1
    stage_half256(A, m0, K, T + 1, 1, Ab1, tid);
    QUAD_(Ab0, 1);
    asm volatile("s_waitcnt lgkmcnt(0)" ::: "memory");
    __builtin_amdgcn_s_barrier();            // frees Bb0 for restage
    __builtin_amdgcn_sched_barrier(0);
    // ph2
    stage_half256(Bm, n0, K, t2, 0, Bb0, tid);
    QUAD_(Ab0, 2);
    // ph3
    stage_half256(Bm, n0, K, t2, 1, Bb0, tid);
    QUAD_(Ab0, 3);
    // B(T+1),A(T+1) landed (leave B(T+2) in flight)
    asm volatile("s_waitcnt vmcnt(2) lgkmcnt(0)" ::: "memory");
    __builtin_amdgcn_s_barrier();
    __builtin_amdgcn_sched_barrier(0);
    // ph4
    stage_half256(A, m0, K, t2, 0, Ab0, tid);
    LOADB_(Bb1); QUAD_(Ab1, 0);
    // ph5
    stage_half256(A, m0, K, t2, 1, Ab0, tid);
    QUAD_(Ab1, 1);
    asm volatile("s_waitcnt lgkmcnt(0)" ::: "memory");
    __builtin_amdgcn_s_barrier();            // frees Bb1 for restage
    __builtin_amdgcn_sched_barrier(0);
    // ph6
    stage_half256(Bm, n0, K, t3, 0, Bb1, tid);
    QUAD_(Ab1, 2);
    // ph7
    stage_half256(Bm, n0, K, t3, 1, Bb1, tid);
    QUAD_(Ab1, 3);
  }
#undef LOADB_
#undef QUAD_
}

// ---------------------------------------------------------------------------
// QKV projection (256² 8-phase): qkv = x @ qkv_w^T ; route to
// Q(*QSCALE)[B,H,N,HD], K[B,H,N,HD], V^T[B,H,HD,N], bf16.
// Each 256-wide n-tile lies wholly in one of Q/K/V (768 = 3 x 256).
// ---------------------------------------------------------------------------
__global__ __launch_bounds__(512, 2) void qkv_gemm(
    const unsigned short* __restrict__ xb, const unsigned short* __restrict__ wb,
    unsigned short* __restrict__ q_s, unsigned short* __restrict__ k_s,
    unsigned short* __restrict__ v_t){
  __shared__ __align__(16) char smem[65536];
  f32x4 acc[8][4];
  #pragma unroll
  for (int i = 0; i < 8; i++)
    #pragma unroll
    for (int j = 0; j < 4; j++){
      acc[i][j][0] = 0.f; acc[i][j][1] = 0.f; acc[i][j][2] = 0.f; acc[i][j][3] = 0.f;
    }
  const int m0 = blockIdx.y * 256, n0 = blockIdx.x * 256;
  gemm_core256(xb, wb, m0, n0, 768, smem, acc);

  const int tid = threadIdx.x, lane = tid & 63, w = tid >> 6;
  const int g = lane >> 4, r16 = lane & 15;
  const int wr = w >> 2, wc = w & 3;
  const int sel = n0 / 768;                       // block-uniform
  #pragma unroll
  for (int mi = 0; mi < 8; mi++){
    int grow = m0 + wr * 128 + mi * 16 + r16;     // 0..16383 = [16][1024]
    int bb = grow >> 10, ii = grow & 1023;
    #pragma unroll
    for (int ni = 0; ni < 4; ni++){
      int gcol0 = n0 + wc * 64 + ni * 16 + 4 * g; // 4-aligned, within one head
      int rem = gcol0 - sel * 768;
      int h = rem >> 6, hd0 = rem & 63;
      size_t base = ((size_t)(bb * 12 + h)) << 16;   // *1024*64
      f32x4 v = acc[mi][ni];
      if (sel == 0){
        ushort4 u;
        u.x = f2bf(v[0] * QSCALE); u.y = f2bf(v[1] * QSCALE);
        u.z = f2bf(v[2] * QSCALE); u.w = f2bf(v[3] * QSCALE);
        *(ushort4*)(q_s + base + ((size_t)ii << 6) + hd0) = u;
      } else if (sel == 1){
        ushort4 u;
        u.x = f2bf(v[0]); u.y = f2bf(v[1]); u.z = f2bf(v[2]); u.w = f2bf(v[3]);
        *(ushort4*)(k_s + base + ((size_t)ii << 6) + hd0) = u;
      } else {
        #pragma unroll
        for (int r = 0; r < 4; r++)
          v_t[base + ((size_t)(hd0 + r) << 10) + ii] = f2bf(v[r]);
      }
    }
  }
}

// ---------------------------------------------------------------------------
// Flash attention with relative-position bias (exp2-domain online softmax,
// defer-max THR=8, pre-swizzled bucket byte offsets, bf16 bias table).
// R7/R13 champion: 64 q-rows/block, 4 waves x 16 rows, LDS 32768 B. FROZEN.
// ---------------------------------------------------------------------------
__global__ __launch_bounds__(256) void attn_kernel(
    const unsigned short* __restrict__ q_s, const unsigned short* __restrict__ k_s,
    const unsigned short* __restrict__ v_t, const unsigned char* __restrict__ rp8,
    const float* __restrict__ rpe, unsigned short* __restrict__ ao){
  __shared__ __align__(16) char smem[32768];
  const int tid = threadIdx.x, lane = tid & 63, w = tid >> 6;
  const int g = lane >> 4, r16 = lane & 15;
  const int qb = blockIdx.x, bh = blockIdx.y;
  const size_t bh_base = (size_t)bh << 16;   // *1024*64 elements

  const int i_loc = w * 16 + r16;
  const size_t qoff = bh_base + ((size_t)(qb * 64 + i_loc) << 6);
  bf16x8 qf0 = *(const bf16x8*)(q_s + qoff + g * 8);
  bf16x8 qf1 = *(const bf16x8*)(q_s + qoff + 32 + g * 8);

  // bias[i][c] = q_i . rpe_c via MFMA; bf16, swizzled; wave-private
  char* bias_lds = smem + 24576;
  const int s16 = (r16 & 7) << 4;
  #pragma unroll
  for (int jt = 0; jt < 4; jt++){
    int crow = jt * 16 + r16;
    bf16x8 a0, a1;
    #pragma unroll
    for (int e = 0; e < 8; e++){ a0[e] = 0; a1[e] = 0; }
    if (crow < 49){
      const float* rr = rpe + crow * 64 + g * 8;
      float4 x0 = *(const float4*)(rr);
      float4 x1 = *(const float4*)(rr + 4);
      float4 y0 = *(const float4*)(rr + 32);
      float4 y1 = *(const float4*)(rr + 36);
      a0[0]=f2bf(x0.x); a0[1]=f2bf(x0.y); a0[2]=f2bf(x0.z); a0[3]=f2bf(x0.w);
      a0[4]=f2bf(x1.x); a0[5]=f2bf(x1.y); a0[6]=f2bf(x1.z); a0[7]=f2bf(x1.w);
      a1[0]=f2bf(y0.x); a1[1]=f2bf(y0.y); a1[2]=f2bf(y0.z); a1[3]=f2bf(y0.w);
      a1[4]=f2bf(y1.x); a1[5]=f2bf(y1.y); a1[6]=f2bf(y1.z); a1[7]=f2bf(y1.w);
    }
    f32x4 z = {0.f, 0.f, 0.f, 0.f};
    z = mfma16(a0, qf0, z);
    z = mfma16(a1, qf1, z);
    uint2 u; u.x = cvt_pk_bf16(z[0], z[1]); u.y = cvt_pk_bf16(z[2], z[3]);
    *(uint2*)(bias_lds + i_loc * 128 + ((jt * 32 + 8 * g) ^ s16)) = u;
  }

  unsigned short* ks = (unsigned short*)smem;
  unsigned short* vs = (unsigned short*)(smem + 8192);
  char* pbuf = smem + 16384 + w * 2048;
  const char* browb = bias_lds + i_loc * 128;

  const int ci0 = tid, ci1 = 256 + tid;
  const int row0 = ci0 >> 3, sc0 = (ci0 & 7) ^ (row0 & 7);
  const int row1 = ci1 >> 3, sc1 = (ci1 & 7) ^ (row1 & 7);
  const char* kp0 = (const char*)(k_s + bh_base) + row0 * 128 + sc0 * 16;
  const char* kp1 = (const char*)(k_s + bh_base) + row1 * 128 + sc1 * 16;
  const char* vp0 = (const char*)(v_t + bh_base) + row0 * 2048 + sc0 * 16;
  const char* vp1 = (const char*)(v_t + bh_base) + row1 * 2048 + sc1 * 16;
  char* kl0 = (char*)smem + w * 1024;
  char* kl1 = (char*)smem + 4096 + w * 1024;
  char* vl0 = (char*)smem + 8192 + w * 1024;
  char* vl1 = (char*)smem + 12288 + w * 1024;
  const unsigned char* rprow = rp8 + ((size_t)(qb * 64 + i_loc) << 10);

  f32x4 o[4];
  #pragma unroll
  for (int dt = 0; dt < 4; dt++){ o[dt][0]=0.f; o[dt][1]=0.f; o[dt][2]=0.f; o[dt][3]=0.f; }
  float m_i = -INFINITY, l_i = 0.f;

  for (int kb = 0; kb < 16; kb++){
    __syncthreads();
    gload_lds16(kp0, kl0);
    gload_lds16(kp1, kl1);
    gload_lds16(vp0, vl0);
    gload_lds16(vp1, vl1);
    kp0 += 8192; kp1 += 8192; vp0 += 128; vp1 += 128;
    __syncthreads();

    f32x4 st[4];
    #pragma unroll
    for (int jt = 0; jt < 4; jt++){
      int krow = jt * 16 + r16;
      int sw = (krow & 7) << 4;
      bf16x8 ka0 = *(const bf16x8*)((char*)ks + krow * 128 + ((g * 16) ^ sw));
      bf16x8 ka1 = *(const bf16x8*)((char*)ks + krow * 128 + ((64 + g * 16) ^ sw));
      f32x4 z = {0.f, 0.f, 0.f, 0.f};
      z = mfma16(ka0, qf0, z);
      z = mfma16(ka1, qf1, z);
      st[jt] = z;
    }
    #pragma unroll
    for (int jt = 0; jt < 4; jt++){
      unsigned bu = *(const unsigned*)(rprow + kb * 64 + jt * 16 + g * 4);
      st[jt][0] += __uint_as_float((unsigned)*(const unsigned short*)(browb + (bu & 0xff)) << 16);
      st[jt][1] += __uint_as_float((unsigned)*(const unsigned short*)(browb + ((bu >> 8) & 0xff)) << 16);
      st[jt][2] += __uint_as_float((unsigned)*(const unsigned short*)(browb + ((bu >> 16) & 0xff)) << 16);
      st[jt][3] += __uint_as_float((unsigned)*(const unsigned short*)(browb + (bu >> 24)) << 16);
    }
    float tmax = -INFINITY;
    #pragma unroll
    for (int jt = 0; jt < 4; jt++)
      tmax = fmaxf(tmax, fmaxf(fmaxf(st[jt][0], st[jt][1]), fmaxf(st[jt][2], st[jt][3])));
    tmax = fmaxf(tmax, __shfl_xor(tmax, 16));
    tmax = fmaxf(tmax, __shfl_xor(tmax, 32));
    const bool skip = __all(tmax <= m_i + 8.f);
    if (!skip){
      float mnew = fmaxf(m_i, tmax);
      float alpha = exp2_fast(m_i - mnew);
      m_i = mnew;
      l_i *= alpha;
      float af[4];
      #pragma unroll
      for (int r = 0; r < 4; r++) af[r] = __shfl(alpha, 4 * g + r);
      #pragma unroll
      for (int dt = 0; dt < 4; dt++){
        o[dt][0] *= af[0]; o[dt][1] *= af[1]; o[dt][2] *= af[2]; o[dt][3] *= af[3];
      }
    }
    #pragma unroll
    for (int jt = 0; jt < 4; jt++){
      float p0 = exp2_fast(st[jt][0] - m_i);
      float p1 = exp2_fast(st[jt][1] - m_i);
      float p2 = exp2_fast(st[jt][2] - m_i);
      float p3 = exp2_fast(st[jt][3] - m_i);
      l_i += (p0 + p1) + (p2 + p3);
      uint2 u; u.x = cvt_pk_bf16(p0, p1); u.y = cvt_pk_bf16(p2, p3);
      *(uint2*)(pbuf + r16 * 128 + ((jt * 32 + g * 8) ^ ((r16 & 7) << 4))) = u;
    }
    #pragma unroll
    for (int kt = 0; kt < 2; kt++){
      bf16x8 pa = *(const bf16x8*)(pbuf + r16 * 128 + ((kt * 64 + g * 16) ^ ((r16 & 7) << 4)));
      #pragma unroll
      for (int dt = 0; dt < 4; dt++){
        int vrow = dt * 16 + r16;
        bf16x8 vb = *(const bf16x8*)((char*)vs + vrow * 128 + ((kt * 64 + g * 16) ^ ((vrow & 7) << 4)));
        o[dt] = mfma16(pa, vb, o[dt]);
      }
    }
  }

  l_i += __shfl_xor(l_i, 16);
  l_i += __shfl_xor(l_i, 32);
  float lf[4];
  #pragma unroll
  for (int r = 0; r < 4; r++) lf[r] = 1.f / __shfl(l_i, 4 * g + r);
  const int bidx = bh / 12, h = bh - bidx * 12;
  #pragma unroll
  for (int dt = 0; dt < 4; dt++){
    int d = dt * 16 + r16;
    #pragma unroll
    for (int r = 0; r < 4; r++){
      int i = qb * 64 + w * 16 + 4 * g + r;
      ao[(size_t)(bidx * 1024 + i) * 768 + h * 64 + d] = f2bf(o[dt][r] * lf[r]);
    }
  }
}

// ---------------------------------------------------------------------------
// Output projection (256² 8-phase): out = attn_out @ proj_w^T + proj_b (f32)
// ---------------------------------------------------------------------------
__global__ __launch_bounds__(512, 2) void proj_gemm(
    const unsigned short* __restrict__ aob, const unsigned short* __restrict__ pwb,
    const float* __restrict__ pb, float* __restrict__ out){
  __shared__ __align__(16) char smem[65536];
  f32x4 acc[8][4];
  #pragma unroll
  for (int i = 0; i < 8; i++)
    #pragma unroll
    for (int j = 0; j < 4; j++){
      acc[i][j][0] = 0.f; acc[i][j][1] = 0.f; acc[i][j][2] = 0.f; acc[i][j][3] = 0.f;
    }
  const int m0 = blockIdx.y * 256, n0 = blockIdx.x * 256;
  gemm_core256(aob, pwb, m0, n0, 768, smem, acc);

  const int tid = threadIdx.x, lane = tid & 63, w = tid >> 6;
  const int g = lane >> 4, r16 = lane & 15;
  const int wr = w >> 2, wc = w & 3;
  #pragma unroll
  for (int mi = 0; mi < 8; mi++){
    int grow = m0 + wr * 128 + mi * 16 + r16;
    #pragma unroll
    for (int ni = 0; ni < 4; ni++){
      int gcol0 = n0 + wc * 64 + ni * 16 + 4 * g;
      float4 b4 = *(const float4*)(pb + gcol0);
      f32x4 v = acc[mi][ni];
      float4 ov;
      ov.x = v[0] + b4.x; ov.y = v[1] + b4.y;
      ov.z = v[2] + b4.z; ov.w = v[3] + b4.w;
      *(float4*)(out + (size_t)grow * 768 + gcol0) = ov;
    }
  }
}

// ---------------------------------------------------------------------------
extern "C" void kernel_launch(void* const* d_in, const int* in_sizes, int n_in,
                              void* d_out, int out_size, void* d_ws, size_t ws_size,
                              hipStream_t stream){
  const float* x      = (const float*)d_in[0];
  const float* qkv_w  = (const float*)d_in[1];
  const float* rpe    = (const float*)d_in[2];
  const int*   rp     = (const int*)d_in[3];
  const float* proj_w = (const float*)d_in[4];
  const float* proj_b = (const float*)d_in[5];
  float* out = (float*)d_out;
  char* ws = (char*)d_ws;

  unsigned short* xb  = (unsigned short*)(ws);               // 25,165,824 B
  unsigned short* wb  = (unsigned short*)(ws + 25165824);    //  3,538,944 B
  unsigned short* pwb = (unsigned short*)(ws + 28704768);    //  1,179,648 B
  unsigned char*  rp8 = (unsigned char*) (ws + 29884416);    //  1,048,576 B
  unsigned short* q_s = (unsigned short*)(ws + 30932992);    // 25,165,824 B
  unsigned short* k_s = (unsigned short*)(ws + 56098816);    // 25,165,824 B
  unsigned short* v_t = (unsigned short*)(ws + 81264640);    // 25,165,824 B
  unsigned short* aob = (unsigned short*)(ws + 106430464);   // 25,165,824 B -> 131,596,288 total

  prep_kernel<<<2048, 256, 0, stream>>>(x, qkv_w, proj_w, rp, xb, wb, pwb, rp8);
  qkv_gemm<<<dim3(9, 64), 512, 0, stream>>>(xb, wb, q_s, k_s, v_t);
  attn_kernel<<<dim3(16, 192), 256, 0, stream>>>(q_s, k_s, v_t, rp8, rpe, aob);
  proj_gemm<<<dim3(3, 64), 512, 0, stream>>>(aob, pwb, proj_b, out);
}